// Round 12
// baseline (915.068 us; speedup 1.0000x reference)
//
#include <hip/hip_runtime.h>
#include <cstdint>
#include <cstddef>

#define NNODES 20000
#define NEDGES 320000
#define HID 512
#define EDIM 64
#define KFEAT (2*HID + EDIM)   // 1088

typedef __bf16 bf16x8 __attribute__((ext_vector_type(8)));
typedef short short8 __attribute__((ext_vector_type(8)));
typedef float f32x4 __attribute__((ext_vector_type(4)));

#define AM_NODE 1
#define AM_DIR  2
#define EP_BF16    0   // +bias, mish, bf16 store
#define EP_F32     2   // +bias, raw f32 store
#define EP_BF16L   3   // no bias, no mish, bf16 store
#define EP_RAW     5   // raw f2bf(acc) store (bias+mish deferred to consumer)

__device__ __forceinline__ uint16_t f2bf(float f){
  uint32_t u = __float_as_uint(f);
  u += 0x7FFFu + ((u >> 16) & 1u);
  return (uint16_t)(u >> 16);
}
__device__ __forceinline__ float bf2f(uint16_t h){
  return __uint_as_float((uint32_t)h << 16);
}
// mish(x) = x * tanh(softplus(x)) = x * (e^2+2e)/(e^2+2e+2), e = exp(x)
__device__ __forceinline__ float mishf(float v){
  float e = __expf(fminf(v, 18.f));
  float n = e * (e + 2.f);
  return v * __fdividef(n, n + 2.f);
}
__device__ __forceinline__ void gl_lds16(const void* g, void* l){
  __builtin_amdgcn_global_load_lds(
      (const __attribute__((address_space(1))) uint32_t*)g,
      (__attribute__((address_space(3))) uint32_t*)l, 16, 0, 0);
}

// ---------------- index dtype detect / normalize ----------------
__global__ void detect_idx(const int* __restrict__ e, int* __restrict__ flag){
  int i = blockIdx.x * 256 + threadIdx.x;   // probe first 16384 pairs
  if (e[2*i + 1] != 0) atomicOr(flag, 1);   // flag=1 -> int32 layout
}
__global__ void norm_idx(const int* __restrict__ e, const int* __restrict__ flag,
                         int* __restrict__ s, int* __restrict__ d){
  int i = blockIdx.x * 256 + threadIdx.x;
  if (i >= NEDGES) return;
  int sv, dv;
  if (*flag){ sv = e[i];     dv = e[NEDGES + i]; }
  else      { sv = e[2*i];   dv = e[2*NEDGES + 2*i]; }   // int64 lo words
  sv = sv < 0 ? 0 : (sv > NNODES-1 ? NNODES-1 : sv);
  dv = dv < 0 ? 0 : (dv > NNODES-1 ? NNODES-1 : dv);
  s[i] = sv; d[i] = dv;
}

// ---------------- counting sort by dst (single permutation) ----------------
__global__ void hist_k(const int* __restrict__ d, int* __restrict__ cnt){
  int i = blockIdx.x * 256 + threadIdx.x;
  if (i < NEDGES) atomicAdd(&cnt[d[i]], 1);
}
__global__ __launch_bounds__(256)
void scan_k(const int* __restrict__ cnt, int* __restrict__ rp, int* __restrict__ cur){
  const int SEG = (NNODES + 255) / 256;
  const int t = threadIdx.x;
  const int lo = t * SEG;
  const int hi = (lo + SEG < NNODES) ? lo + SEG : NNODES;
  int s = 0;
  for (int i = lo; i < hi; ++i) s += cnt[i];
  __shared__ int sh[256];
  sh[t] = s; __syncthreads();
  for (int o = 1; o < 256; o <<= 1){
    int v = (t >= o) ? sh[t - o] : 0;
    __syncthreads();
    sh[t] += v;
    __syncthreads();
  }
  int pre = t ? sh[t-1] : 0;
  for (int i = lo; i < hi; ++i){
    rp[i] = pre; cur[i] = pre; pre += cnt[i];
  }
  if (t == 255) rp[NNODES] = sh[255];
}
// ONE permutation: sorted position p gets src id AND original edge id.
__global__ void permute_k(const int* __restrict__ srcN, const int* __restrict__ dstN,
                          int* __restrict__ cur, int* __restrict__ srcS,
                          int* __restrict__ eidx){
  int i = blockIdx.x * 256 + threadIdx.x;
  if (i < NEDGES){
    int d = dstN[i];
    int p = atomicAdd(&cur[d], 1);
    srcS[p] = srcN[i];
    eidx[p] = i;
  }
}
__global__ void fill_dstS(const int* __restrict__ rp, int* __restrict__ dstS){
  int n = blockIdx.x;
  int lo = rp[n], hi = rp[n+1];
  for (int e = lo + threadIdx.x; e < hi; e += 64) dstS[e] = n;
}

// ---------------- casts ----------------
__global__ void cast_bf16_vec(const float4* __restrict__ in, ushort4* __restrict__ out, int n4){
  int i = blockIdx.x * 256 + threadIdx.x;
  if (i < n4){
    float4 v = in[i];
    ushort4 o; o.x = f2bf(v.x); o.y = f2bf(v.y); o.z = f2bf(v.z); o.w = f2bf(v.w);
    out[i] = o;
  }
}
__global__ void transpose_cast(const float* __restrict__ W, uint16_t* __restrict__ WT, int K, int N){
  int k = blockIdx.x * 256 + threadIdx.x;
  int n = blockIdx.y;
  if (k < K) WT[(size_t)n * K + k] = f2bf(W[(size_t)k * N + n]);
}

// ---------------- fused MFMA GEMM (128x128 tile, BK=64, 4 waves) ----------------
// Block remap: when nty%8==0, group row panels per XCD (flat%8 == XCD round-robin):
//   xcd = flat&7, i = flat>>3, by = xcd*(nty/8) + i/ntx, bx = i%ntx
// AM_NODE: row gm = [xb[gm] | aggb[gm]]  (K = 1024)
// AM_DIR : row-major A0, stride KTOT
// BPQ=1  : B^T row n -> w1t + (n&511)*bstr + (n>>9)*512  (fused P|Q, N=1024)
template<int AMODE, int EPI, int KTOT, int BPQ>
__global__ __launch_bounds__(256, 2)
void gemm_k(const uint16_t* __restrict__ A0, const uint16_t* __restrict__ A1,
            const uint16_t* __restrict__ BT, const float* __restrict__ bias,
            uint16_t* __restrict__ Cb, float* __restrict__ Cf,
            int bstr, int cstr, int m0base, int M, int crowOff)
{
  __shared__ __align__(16) char smem[32768];
  char* As = smem;
  char* Bs = smem + 16384;
  const int t = threadIdx.x;
  const int ntx = gridDim.x, nty = gridDim.y;
  int bx = blockIdx.x, by = blockIdx.y;
  if ((nty & 7) == 0){
    int flat = by * ntx + bx;
    int xcd = flat & 7;
    int i = flat >> 3;
    by = xcd * (nty >> 3) + i / ntx;
    bx = i % ntx;
  }
  const int m0 = m0base + by * 128;
  const int n0 = bx * 128;
  const int srow = t >> 3;
  const int c8   = t & 7;
  const int scol = ((c8 ^ (srow & 7)) << 3);
  const int ldst = srow * 128 + c8 * 16;

  const uint16_t* as0[4]; const uint16_t* as1[4];
  #pragma unroll
  for (int i = 0; i < 4; ++i){
    int gm = m0 + srow + 32*i;
    if (gm > M - 1) gm = M - 1;
    if (AMODE == AM_NODE){
      as0[i] = A0 + (size_t)gm * HID;
      as1[i] = A1 + (size_t)gm * HID;
    } else {
      as0[i] = A0 + (size_t)gm * KTOT;
      as1[i] = A0;
    }
  }
  const uint16_t* brow[4];
  #pragma unroll
  for (int i = 0; i < 4; ++i){
    int nr = n0 + srow + 32*i;
    if (BPQ) brow[i] = BT + (size_t)(nr & (HID-1))*bstr + (nr >> 9)*HID;
    else     brow[i] = BT + (size_t)nr*bstr;
  }

  const int lane = t & 63;
  const int wv = t >> 6;
  const int wm = (wv >> 1) * 64;
  const int wn = (wv & 1) * 64;
  const int l15 = lane & 15;
  const int lk16 = (lane >> 4) << 4;
  const int swz = (l15 & 7) << 4;

  f32x4 acc[4][4] = {};

  const int NK = KTOT / 64;
  for (int kk = 0; kk < NK; ++kk){
    const int k0 = kk * 64;
    #pragma unroll
    for (int i = 0; i < 4; ++i){
      const uint16_t* g;
      if (AMODE == AM_NODE){
        g = (k0 < HID) ? as0[i] + (k0 + scol) : as1[i] + (k0 - HID + scol);
      } else {
        g = as0[i] + (k0 + scol);
      }
      gl_lds16(g, As + i*4096 + ldst);
    }
    #pragma unroll
    for (int i = 0; i < 4; ++i)
      gl_lds16(brow[i] + (k0 + scol), Bs + i*4096 + ldst);
    __syncthreads();
    #pragma unroll
    for (int ks = 0; ks < 2; ++ks){
      bf16x8 af[4], bfr[4];
      #pragma unroll
      for (int i = 0; i < 4; ++i){
        const int ar = wm + i*16 + l15;
        af[i] = *(const bf16x8*)(As + ar*128 + ((ks*64 + lk16) ^ swz));
      }
      #pragma unroll
      for (int j = 0; j < 4; ++j){
        const int br = wn + j*16 + l15;
        bfr[j] = *(const bf16x8*)(Bs + br*128 + ((ks*64 + lk16) ^ swz));
      }
      #pragma unroll
      for (int i = 0; i < 4; ++i)
        #pragma unroll
        for (int j = 0; j < 4; ++j)
          acc[i][j] = __builtin_amdgcn_mfma_f32_16x16x32_bf16(af[i], bfr[j], acc[i][j], 0, 0, 0);
    }
    __syncthreads();
  }

  #pragma unroll
  for (int i = 0; i < 4; ++i){
    const int rb = wm + i*16 + ((lane >> 4) << 2);
    #pragma unroll
    for (int j = 0; j < 4; ++j){
      const int gcol = n0 + wn + j*16 + l15;
      const float bv = (EPI == EP_BF16L || EPI == EP_RAW) ? 0.f : bias[gcol];
      #pragma unroll
      for (int r = 0; r < 4; ++r){
        const int grow = m0 + rb + r;
        if (grow < M){
          float v = acc[i][j][r] + bv;
          if (EPI == EP_BF16){
            Cb[(size_t)(grow - crowOff) * cstr + gcol] = f2bf(mishf(v));
          } else if (EPI == EP_BF16L || EPI == EP_RAW){
            Cb[(size_t)(grow - crowOff) * cstr + gcol] = f2bf(v);
          } else {
            Cf[(size_t)grow * cstr + gcol] = v;
          }
        }
      }
    }
  }
}

// ---------------- EH: h = mish(ea@W1c + P[src] + Q[dst] + b1) ----------------
// 256 threads = 4 waves; block = 32 edges x 512 cols; wave wv owns cols [wv*128, +128).
// T14 pipeline: P/Q gathers for iteration 0 issued BEFORE the MFMA phase; inside the
// 8-iter epilogue, iteration i+1's gathers are issued before iteration i's compute.
__global__ __launch_bounds__(256, 4)
void eh_k(const uint16_t* __restrict__ eab, const uint16_t* __restrict__ PQb,
          const int* __restrict__ idx,
          const uint16_t* __restrict__ w1t, const float* __restrict__ b1,
          uint16_t* __restrict__ hb, int m0base, int crowOff)
{
  __shared__ __align__(16) char smem[32768];   // 4 waves x 8KB (16 rows x 512B)
  const int t = threadIdx.x;
  const int m0 = m0base + blockIdx.x * 32;
  const int lane = t & 63;
  const int wv = t >> 6;
  const int l15 = lane & 15;
  const int lg = lane >> 4;                    // 0..3
  const int* srcS = idx;
  const int* dstS = idx + NEDGES;
  const int* eidx = idx + 2*NEDGES;

  int eidxr[2];
  #pragma unroll
  for (int fr = 0; fr < 2; ++fr) eidxr[fr] = eidx[m0 + fr*16 + l15];

  // ---- prefetch it=0 P/Q (hides under the MFMA phase)
  const int pqoff = wv*128 + l15*4;
  ushort4 cp0, cp1, cq0, cq1, np0, np1, nq0, nq1;
  {
    int s0 = srcS[m0 + lg];          // it=0: fr=0, i=0, row=lg
    int d0 = dstS[m0 + lg];
    const uint16_t* pb = PQb + (size_t)s0*1024 + pqoff;
    const uint16_t* qb = PQb + (size_t)d0*1024 + 512 + pqoff;
    cp0 = *(const ushort4*)pb;  cp1 = *(const ushort4*)(pb + 64);
    cq0 = *(const ushort4*)qb;  cq1 = *(const ushort4*)(qb + 64);
  }

  f32x4 acc[2][8] = {};
  #pragma unroll
  for (int ks = 0; ks < 2; ++ks){
    bf16x8 bF[8];
    #pragma unroll
    for (int fc = 0; fc < 8; ++fc){
      int n = wv*128 + fc*16 + l15;
      bF[fc] = *(const bf16x8*)(w1t + (size_t)n*KFEAT + 2*HID + ks*32 + lg*8);
    }
    #pragma unroll
    for (int fr = 0; fr < 2; ++fr){
      bf16x8 av = *(const bf16x8*)(eab + (size_t)eidxr[fr]*EDIM + ks*32 + lg*8);
      #pragma unroll
      for (int fc = 0; fc < 8; ++fc)
        acc[fr][fc] = __builtin_amdgcn_mfma_f32_16x16x32_bf16(av, bF[fc], acc[fr][fc], 0, 0, 0);
    }
  }

  // ---- epilogue: slab transpose + pipelined P/Q + mish + store
  char* slab = smem + wv*8192;
  const float4 b1v0 = *(const float4*)(b1 + wv*128 + l15*4);
  const float4 b1v1 = *(const float4*)(b1 + wv*128 + 64 + l15*4);
  #pragma unroll
  for (int fr = 0; fr < 2; ++fr){
    #pragma unroll
    for (int fc = 0; fc < 8; ++fc){
      #pragma unroll
      for (int r = 0; r < 4; ++r){
        int row = lg*4 + r;                    // row>>2 == lg
        int cb = ((fc*16 + l15)*4) ^ ((lg & 1) << 6);
        *(float*)(slab + row*512 + cb) = acc[fr][fc][r];
      }
    }
    asm volatile("s_waitcnt lgkmcnt(0)" ::: "memory");
    __builtin_amdgcn_sched_barrier(0);
    #pragma unroll
    for (int i = 0; i < 4; ++i){
      const int it = fr*4 + i;
      if (it < 7){                             // prefetch it+1
        int i2 = (it + 1) & 3, f2 = (it + 1) >> 2;
        int row2 = i2*4 + lg;
        int s = srcS[m0 + f2*16 + row2];
        int d = dstS[m0 + f2*16 + row2];
        const uint16_t* pb = PQb + (size_t)s*1024 + pqoff;
        const uint16_t* qb = PQb + (size_t)d*1024 + 512 + pqoff;
        np0 = *(const ushort4*)pb;  np1 = *(const ushort4*)(pb + 64);
        nq0 = *(const ushort4*)qb;  nq1 = *(const ushort4*)(qb + 64);
      }
      int row = i*4 + lg;                      // row>>2 == i
      int grow = m0 + fr*16 + row;
      float4 v0 = *(const float4*)(slab + row*512 + ((l15*16) ^ ((i & 1) << 6)));
      float4 v1 = *(const float4*)(slab + row*512 + ((256 + l15*16) ^ ((i & 1) << 6)));
      ushort4 h0, h1;
      h0.x = f2bf(mishf(v0.x + bf2f(cp0.x) + bf2f(cq0.x) + b1v0.x));
      h0.y = f2bf(mishf(v0.y + bf2f(cp0.y) + bf2f(cq0.y) + b1v0.y));
      h0.z = f2bf(mishf(v0.z + bf2f(cp0.z) + bf2f(cq0.z) + b1v0.z));
      h0.w = f2bf(mishf(v0.w + bf2f(cp0.w) + bf2f(cq0.w) + b1v0.w));
      h1.x = f2bf(mishf(v1.x + bf2f(cp1.x) + bf2f(cq1.x) + b1v1.x));
      h1.y = f2bf(mishf(v1.y + bf2f(cp1.y) + bf2f(cq1.y) + b1v1.y));
      h1.z = f2bf(mishf(v1.z + bf2f(cp1.z) + bf2f(cq1.z) + b1v1.z));
      h1.w = f2bf(mishf(v1.w + bf2f(cp1.w) + bf2f(cq1.w) + b1v1.w));
      size_t hrow = (size_t)(grow - crowOff) * HID + wv*128;
      *(ushort4*)(hb + hrow + l15*4) = h0;
      *(ushort4*)(hb + hrow + 64 + l15*4) = h1;
      cp0 = np0; cp1 = np1; cq0 = nq0; cq1 = nq1;
    }
    asm volatile("s_waitcnt lgkmcnt(0)" ::: "memory");
    __builtin_amdgcn_sched_barrier(0);
  }
}

// ---- CSR gather-reduce with deferred bias+mish; final chunk also writes aggb ----
__global__ __launch_bounds__(128)
void gather_agg(const uint16_t* __restrict__ msg, const int* __restrict__ rp,
                const float* __restrict__ b2, float* __restrict__ agg,
                uint16_t* __restrict__ aggb, int e0, int e1, int fin){
  const int n = blockIdx.x;
  int lo = rp[n], hi = rp[n+1];
  if (lo < e0) lo = e0;
  if (hi > e1) hi = e1;
  if (!fin && lo >= hi) return;
  const int t = threadIdx.x;
  const float4 bv = ((const float4*)b2)[t];
  float4 a = {0.f, 0.f, 0.f, 0.f};
  for (int e = lo; e < hi; ++e){
    ushort4 m = ((const ushort4*)(msg + (size_t)(e - e0) * HID))[t];
    a.x += mishf(bf2f(m.x) + bv.x);
    a.y += mishf(bf2f(m.y) + bv.y);
    a.z += mishf(bf2f(m.z) + bv.z);
    a.w += mishf(bf2f(m.w) + bv.w);
  }
  float4* ap = ((float4*)(agg + (size_t)n * HID)) + t;
  float4 c = *ap;
  c.x += a.x; c.y += a.y; c.z += a.z; c.w += a.w;
  if (lo < hi) *ap = c;
  if (fin){
    ushort4 o;
    o.x = f2bf(c.x); o.y = f2bf(c.y); o.z = f2bf(c.z); o.w = f2bf(c.w);
    ((ushort4*)(aggb + (size_t)n * HID))[t] = o;
  }
}

// ---------------- residual + LayerNorm ----------------
__global__ __launch_bounds__(128)
void resid_ln(const float* __restrict__ x, const float* __restrict__ ob,
              const float* __restrict__ gamma, const float* __restrict__ beta,
              float* __restrict__ y){
  const int row = blockIdx.x;
  const int t = threadIdx.x;
  const float4 xv = ((const float4*)(x + (size_t)row * HID))[t];
  const float4 ov = ((const float4*)(ob + (size_t)row * HID))[t];
  float4 s4;
  s4.x = xv.x + ov.x; s4.y = xv.y + ov.y; s4.z = xv.z + ov.z; s4.w = xv.w + ov.w;
  float s = s4.x + s4.y + s4.z + s4.w;
  float q = s4.x*s4.x + s4.y*s4.y + s4.z*s4.z + s4.w*s4.w;
  #pragma unroll
  for (int o = 32; o; o >>= 1){
    s += __shfl_xor(s, o, 64);
    q += __shfl_xor(q, o, 64);
  }
  __shared__ float ss[2], qq[2];
  if ((t & 63) == 0){ ss[t >> 6] = s; qq[t >> 6] = q; }
  __syncthreads();
  const float S = ss[0] + ss[1], Q = qq[0] + qq[1];
  const float mu = S * (1.0f / HID);
  const float var = Q * (1.0f / HID) - mu * mu;
  const float inv = rsqrtf(var + 1e-5f);
  const float4 g = ((const float4*)gamma)[t];
  const float4 b = ((const float4*)beta)[t];
  float4 o;
  o.x = (s4.x - mu) * inv * g.x + b.x;
  o.y = (s4.y - mu) * inv * g.y + b.y;
  o.z = (s4.z - mu) * inv * g.z + b.z;
  o.w = (s4.w - mu) * inv * g.w + b.w;
  ((float4*)(y + (size_t)row * HID))[t] = o;
}

extern "C" void kernel_launch(void* const* d_in, const int* in_sizes, int n_in,
                              void* d_out, int out_size, void* d_ws, size_t ws_size,
                              hipStream_t stream)
{
  const float* x    = (const float*)d_in[0];
  const int*   ei   = (const int*)d_in[1];
  const float* ea   = (const float*)d_in[2];
  const float* W1   = (const float*)d_in[3];
  const float* b1   = (const float*)d_in[4];
  const float* W2   = (const float*)d_in[5];
  const float* b2   = (const float*)d_in[6];
  const float* W3   = (const float*)d_in[7];
  const float* b3   = (const float*)d_in[8];
  const float* W4   = (const float*)d_in[9];
  const float* b4   = (const float*)d_in[10];
  const float* gmm  = (const float*)d_in[11];
  const float* bet  = (const float*)d_in[12];
  float* out = (float*)d_out;

  uint8_t* w = (uint8_t*)d_ws;
  size_t off = 0;
  auto alloc = [&](size_t bytes) -> void* {
    void* p = w + off;
    off += (bytes + 255) & ~(size_t)255;
    return p;
  };
  uint16_t* xb   = (uint16_t*)alloc((size_t)NNODES*HID*2);
  uint16_t* w1t  = (uint16_t*)alloc((size_t)HID*KFEAT*2);
  uint16_t* w2t  = (uint16_t*)alloc((size_t)HID*HID*2);
  uint16_t* w3t  = (uint16_t*)alloc((size_t)HID*1024*2);
  uint16_t* w4t  = (uint16_t*)alloc((size_t)HID*HID*2);
  uint16_t* PQb  = (uint16_t*)alloc((size_t)NNODES*1024*2);   // [n][1024]: P|Q
  float*    agg  = (float*)alloc((size_t)NNODES*HID*4);
  float*    outf = (float*)alloc((size_t)NNODES*HID*4);
  int*      srcN = (int*)alloc((size_t)NEDGES*4);
  int*      dstN = (int*)alloc((size_t)NEDGES*4);
  int*      idxS = (int*)alloc((size_t)NEDGES*4*3);  // [srcS | dstS | eidx]
  int*      cnt  = (int*)alloc((size_t)NNODES*4);
  int*      rp   = (int*)alloc((size_t)(NNODES+1)*4);
  int*      cur  = (int*)alloc((size_t)NNODES*4);
  int*      flag = (int*)alloc(256);
  int*      srcS = idxS;
  int*      dstS = idxS + NEDGES;
  int*      eidx = idxS + 2*NEDGES;

  // Aliases (lifetime-checked):
  // eab (41 MB)   aliases outf  — eab dead before GEMM4 writes outf.
  // aggb (20.5MB) aliases PQb[0:half]  — PQb dead after last eh_k; aggb written after.
  // ub   (20.5MB) aliases PQb[half:]   — written by GEMM3 after aggb exists; disjoint.
  uint16_t* eab  = (uint16_t*)outf;
  uint16_t* aggb = PQb;
  uint16_t* ub   = PQb + (size_t)NNODES*HID;

  size_t remain = (ws_size > off) ? ws_size - off : 0;
  size_t maxChunk = remain / ((size_t)HID*2*2);    // hb + msgb
  long long chunkE = (long long)(maxChunk & ~(size_t)1023);  // %1024 -> nty%8==0
  if (chunkE > NEDGES) chunkE = NEDGES;
  if (chunkE < 1024) chunkE = 1024;
  uint16_t* hb   = (uint16_t*)alloc((size_t)chunkE*HID*2);
  uint16_t* msgb = (uint16_t*)alloc((size_t)chunkE*HID*2);

  hipMemsetAsync(agg, 0, (size_t)NNODES*HID*4, stream);
  hipMemsetAsync(cnt, 0, (size_t)NNODES*4, stream);
  hipMemsetAsync(flag, 0, 4, stream);

  detect_idx<<<64, 256, 0, stream>>>(ei, flag);
  norm_idx<<<(NEDGES+255)/256, 256, 0, stream>>>(ei, flag, srcN, dstN);
  hist_k<<<(NEDGES+255)/256, 256, 0, stream>>>(dstN, cnt);
  scan_k<<<1, 256, 0, stream>>>(cnt, rp, cur);
  permute_k<<<(NEDGES+255)/256, 256, 0, stream>>>(srcN, dstN, cur, srcS, eidx);
  fill_dstS<<<NNODES, 64, 0, stream>>>(rp, dstS);

  cast_bf16_vec<<<(NNODES*HID/4+255)/256, 256, 0, stream>>>((const float4*)x, (ushort4*)xb, NNODES*HID/4);
  cast_bf16_vec<<<(NEDGES*EDIM/4+255)/256, 256, 0, stream>>>((const float4*)ea, (ushort4*)eab, NEDGES*EDIM/4);

  transpose_cast<<<dim3((KFEAT+255)/256, HID), 256, 0, stream>>>(W1, w1t, KFEAT, HID);
  transpose_cast<<<dim3((HID+255)/256,   HID), 256, 0, stream>>>(W2, w2t, HID, HID);
  transpose_cast<<<dim3((1024+255)/256,  HID), 256, 0, stream>>>(W3, w3t, 1024, HID);
  transpose_cast<<<dim3((HID+255)/256,   HID), 256, 0, stream>>>(W4, w4t, HID, HID);

  // Fused P|Q = x @ [W1a | W1b]  (N=1024, bf16 output, no bias/act)
  // nty=160 (%8==0 -> XCD grouping; padded tiles clamp rows, write-guarded)
  dim3 gpq(1024/128, 160);
  gemm_k<AM_DIR, EP_BF16L, HID, 1><<<gpq, 256, 0, stream>>>(
      xb, nullptr, w1t, b1, PQb, nullptr, KFEAT, 1024, 0, NNODES, 0);

  for (long long e0 = 0; e0 < NEDGES; e0 += chunkE){
    int ce = (int)((NEDGES - e0 < chunkE) ? (NEDGES - e0) : chunkE);
    int fin = (e0 + chunkE >= NEDGES) ? 1 : 0;
    // EH: h = mish(ea@W1c + P[src] + Q[dst] + b1) -> hb (chunk-local)
    eh_k<<<(ce+31)/32, 256, 0, stream>>>(eab, PQb, idxS, w1t, b1, hb, (int)e0, (int)e0);
    // GEMM2: hb @ W2 -> raw bf16 msgb (bias+mish deferred to gather)
    dim3 g2(HID/128, (ce+127)/128);
    gemm_k<AM_DIR, EP_RAW, HID, 0><<<g2, 256, 0, stream>>>(
        hb, nullptr, w2t, b2, msgb, nullptr, HID, HID, 0, ce, 0);
    // CSR gather-reduce: agg[n] += mish(msg + b2); final chunk also emits aggb
    gather_agg<<<NNODES, 128, 0, stream>>>(msgb, rp, b2, agg, aggb,
                                           (int)e0, (int)(e0+ce), fin);
  }

  dim3 g3(HID/128, 160);
  gemm_k<AM_NODE, EP_BF16, 1024, 0><<<g3, 256, 0, stream>>>(
      xb, aggb, w3t, b3, ub, nullptr, 1024, HID, 0, NNODES, 0);
  gemm_k<AM_DIR, EP_F32, HID, 0><<<g3, 256, 0, stream>>>(
      ub, nullptr, w4t, b4, nullptr, outf, HID, HID, 0, NNODES, 0);

  resid_ln<<<NNODES, 128, 0, stream>>>(x, outf, gmm, bet, out);
}

// Round 13
// 913.108 us; speedup vs baseline: 1.0021x; 1.0021x over previous
//
#include <hip/hip_runtime.h>
#include <cstdint>
#include <cstddef>

#define NNODES 20000
#define NEDGES 320000
#define HID 512
#define EDIM 64
#define KFEAT (2*HID + EDIM)   // 1088

typedef __bf16 bf16x8 __attribute__((ext_vector_type(8)));
typedef short short8 __attribute__((ext_vector_type(8)));
typedef float f32x4 __attribute__((ext_vector_type(4)));

#define AM_NODE 1
#define AM_DIR  2
#define EP_BF16    0   // +bias, mish, bf16 store
#define EP_F32     2   // +bias, raw f32 store
#define EP_BF16L   3   // no bias, no mish, bf16 store
#define EP_RAW     5   // raw f2bf(acc) store (bias+mish deferred to consumer)

__device__ __forceinline__ uint16_t f2bf(float f){
  uint32_t u = __float_as_uint(f);
  u += 0x7FFFu + ((u >> 16) & 1u);
  return (uint16_t)(u >> 16);
}
__device__ __forceinline__ float bf2f(uint16_t h){
  return __uint_as_float((uint32_t)h << 16);
}
// mish(x) = x * tanh(softplus(x)) = x * (e^2+2e)/(e^2+2e+2), e = exp(x)
__device__ __forceinline__ float mishf(float v){
  float e = __expf(fminf(v, 18.f));
  float n = e * (e + 2.f);
  return v * __fdividef(n, n + 2.f);
}
__device__ __forceinline__ void gl_lds16(const void* g, void* l){
  __builtin_amdgcn_global_load_lds(
      (const __attribute__((address_space(1))) uint32_t*)g,
      (__attribute__((address_space(3))) uint32_t*)l, 16, 0, 0);
}

// ---------------- index dtype detect / normalize ----------------
__global__ void detect_idx(const int* __restrict__ e, int* __restrict__ flag){
  int i = blockIdx.x * 256 + threadIdx.x;   // probe first 16384 pairs
  if (e[2*i + 1] != 0) atomicOr(flag, 1);   // flag=1 -> int32 layout
}
__global__ void norm_idx(const int* __restrict__ e, const int* __restrict__ flag,
                         int* __restrict__ s, int* __restrict__ d){
  int i = blockIdx.x * 256 + threadIdx.x;
  if (i >= NEDGES) return;
  int sv, dv;
  if (*flag){ sv = e[i];     dv = e[NEDGES + i]; }
  else      { sv = e[2*i];   dv = e[2*NEDGES + 2*i]; }   // int64 lo words
  sv = sv < 0 ? 0 : (sv > NNODES-1 ? NNODES-1 : sv);
  dv = dv < 0 ? 0 : (dv > NNODES-1 ? NNODES-1 : dv);
  s[i] = sv; d[i] = dv;
}

// ---------------- counting sort by dst (single permutation) ----------------
__global__ void hist_k(const int* __restrict__ d, int* __restrict__ cnt){
  int i = blockIdx.x * 256 + threadIdx.x;
  if (i < NEDGES) atomicAdd(&cnt[d[i]], 1);
}
__global__ __launch_bounds__(256)
void scan_k(const int* __restrict__ cnt, int* __restrict__ rp, int* __restrict__ cur){
  const int SEG = (NNODES + 255) / 256;
  const int t = threadIdx.x;
  const int lo = t * SEG;
  const int hi = (lo + SEG < NNODES) ? lo + SEG : NNODES;
  int s = 0;
  for (int i = lo; i < hi; ++i) s += cnt[i];
  __shared__ int sh[256];
  sh[t] = s; __syncthreads();
  for (int o = 1; o < 256; o <<= 1){
    int v = (t >= o) ? sh[t - o] : 0;
    __syncthreads();
    sh[t] += v;
    __syncthreads();
  }
  int pre = t ? sh[t-1] : 0;
  for (int i = lo; i < hi; ++i){
    rp[i] = pre; cur[i] = pre; pre += cnt[i];
  }
  if (t == 255) rp[NNODES] = sh[255];
}
// ONE permutation: sorted position p gets src id AND original edge id.
__global__ void permute_k(const int* __restrict__ srcN, const int* __restrict__ dstN,
                          int* __restrict__ cur, int* __restrict__ srcS,
                          int* __restrict__ eidx){
  int i = blockIdx.x * 256 + threadIdx.x;
  if (i < NEDGES){
    int d = dstN[i];
    int p = atomicAdd(&cur[d], 1);
    srcS[p] = srcN[i];
    eidx[p] = i;
  }
}
__global__ void fill_dstS(const int* __restrict__ rp, int* __restrict__ dstS){
  int n = blockIdx.x;
  int lo = rp[n], hi = rp[n+1];
  for (int e = lo + threadIdx.x; e < hi; e += 64) dstS[e] = n;
}

// ---------------- casts ----------------
__global__ void cast_bf16_vec(const float4* __restrict__ in, ushort4* __restrict__ out, int n4){
  int i = blockIdx.x * 256 + threadIdx.x;
  if (i < n4){
    float4 v = in[i];
    ushort4 o; o.x = f2bf(v.x); o.y = f2bf(v.y); o.z = f2bf(v.z); o.w = f2bf(v.w);
    out[i] = o;
  }
}
__global__ void transpose_cast(const float* __restrict__ W, uint16_t* __restrict__ WT, int K, int N){
  int k = blockIdx.x * 256 + threadIdx.x;
  int n = blockIdx.y;
  if (k < K) WT[(size_t)n * K + k] = f2bf(W[(size_t)k * N + n]);
}

// ---------------- fused MFMA GEMM (128x128 tile, BK=64, 4 waves) ----------------
// Block remap: when nty%8==0, group row panels per XCD (flat%8 == XCD round-robin):
//   xcd = flat&7, i = flat>>3, by = xcd*(nty/8) + i/ntx, bx = i%ntx
// AM_NODE: row gm = [xb[gm] | aggb[gm]]  (K = 1024)
// AM_DIR : row-major A0, stride KTOT
// BPQ=1  : B^T row n -> w1t + (n&511)*bstr + (n>>9)*512  (fused P|Q, N=1024)
template<int AMODE, int EPI, int KTOT, int BPQ>
__global__ __launch_bounds__(256, 2)
void gemm_k(const uint16_t* __restrict__ A0, const uint16_t* __restrict__ A1,
            const uint16_t* __restrict__ BT, const float* __restrict__ bias,
            uint16_t* __restrict__ Cb, float* __restrict__ Cf,
            int bstr, int cstr, int m0base, int M, int crowOff)
{
  __shared__ __align__(16) char smem[32768];
  char* As = smem;
  char* Bs = smem + 16384;
  const int t = threadIdx.x;
  const int ntx = gridDim.x, nty = gridDim.y;
  int bx = blockIdx.x, by = blockIdx.y;
  if ((nty & 7) == 0){
    int flat = by * ntx + bx;
    int xcd = flat & 7;
    int i = flat >> 3;
    by = xcd * (nty >> 3) + i / ntx;
    bx = i % ntx;
  }
  const int m0 = m0base + by * 128;
  const int n0 = bx * 128;
  const int srow = t >> 3;
  const int c8   = t & 7;
  const int scol = ((c8 ^ (srow & 7)) << 3);
  const int ldst = srow * 128 + c8 * 16;

  const uint16_t* as0[4]; const uint16_t* as1[4];
  #pragma unroll
  for (int i = 0; i < 4; ++i){
    int gm = m0 + srow + 32*i;
    if (gm > M - 1) gm = M - 1;
    if (AMODE == AM_NODE){
      as0[i] = A0 + (size_t)gm * HID;
      as1[i] = A1 + (size_t)gm * HID;
    } else {
      as0[i] = A0 + (size_t)gm * KTOT;
      as1[i] = A0;
    }
  }
  const uint16_t* brow[4];
  #pragma unroll
  for (int i = 0; i < 4; ++i){
    int nr = n0 + srow + 32*i;
    if (BPQ) brow[i] = BT + (size_t)(nr & (HID-1))*bstr + (nr >> 9)*HID;
    else     brow[i] = BT + (size_t)nr*bstr;
  }

  const int lane = t & 63;
  const int wv = t >> 6;
  const int wm = (wv >> 1) * 64;
  const int wn = (wv & 1) * 64;
  const int l15 = lane & 15;
  const int lk16 = (lane >> 4) << 4;
  const int swz = (l15 & 7) << 4;

  f32x4 acc[4][4] = {};

  const int NK = KTOT / 64;
  for (int kk = 0; kk < NK; ++kk){
    const int k0 = kk * 64;
    #pragma unroll
    for (int i = 0; i < 4; ++i){
      const uint16_t* g;
      if (AMODE == AM_NODE){
        g = (k0 < HID) ? as0[i] + (k0 + scol) : as1[i] + (k0 - HID + scol);
      } else {
        g = as0[i] + (k0 + scol);
      }
      gl_lds16(g, As + i*4096 + ldst);
    }
    #pragma unroll
    for (int i = 0; i < 4; ++i)
      gl_lds16(brow[i] + (k0 + scol), Bs + i*4096 + ldst);
    __syncthreads();
    #pragma unroll
    for (int ks = 0; ks < 2; ++ks){
      bf16x8 af[4], bfr[4];
      #pragma unroll
      for (int i = 0; i < 4; ++i){
        const int ar = wm + i*16 + l15;
        af[i] = *(const bf16x8*)(As + ar*128 + ((ks*64 + lk16) ^ swz));
      }
      #pragma unroll
      for (int j = 0; j < 4; ++j){
        const int br = wn + j*16 + l15;
        bfr[j] = *(const bf16x8*)(Bs + br*128 + ((ks*64 + lk16) ^ swz));
      }
      #pragma unroll
      for (int i = 0; i < 4; ++i)
        #pragma unroll
        for (int j = 0; j < 4; ++j)
          acc[i][j] = __builtin_amdgcn_mfma_f32_16x16x32_bf16(af[i], bfr[j], acc[i][j], 0, 0, 0);
    }
    __syncthreads();
  }

  #pragma unroll
  for (int i = 0; i < 4; ++i){
    const int rb = wm + i*16 + ((lane >> 4) << 2);
    #pragma unroll
    for (int j = 0; j < 4; ++j){
      const int gcol = n0 + wn + j*16 + l15;
      const float bv = (EPI == EP_BF16L || EPI == EP_RAW) ? 0.f : bias[gcol];
      #pragma unroll
      for (int r = 0; r < 4; ++r){
        const int grow = m0 + rb + r;
        if (grow < M){
          float v = acc[i][j][r] + bv;
          if (EPI == EP_BF16){
            Cb[(size_t)(grow - crowOff) * cstr + gcol] = f2bf(mishf(v));
          } else if (EPI == EP_BF16L || EPI == EP_RAW){
            Cb[(size_t)(grow - crowOff) * cstr + gcol] = f2bf(v);
          } else {
            Cf[(size_t)grow * cstr + gcol] = v;
          }
        }
      }
    }
  }
}

// ---------------- EH: h = mish(ea@W1c + P[src] + Q[dst] + b1) ----------------
// 256 threads = 4 waves; block = 32 edges x 512 cols; wave wv owns cols [wv*128, +128).
// Pipeline v3: ALL 8 iterations' (src,dst) indices preloaded at kernel start;
// P/Q gathers double-buffered at DEPTH 2 (it=0,1 issued before the MFMA phase;
// iteration it consumes its buffer then issues it+2's loads into the same set).
__global__ __launch_bounds__(256, 4)
void eh_k(const uint16_t* __restrict__ eab, const uint16_t* __restrict__ PQb,
          const int* __restrict__ idx,
          const uint16_t* __restrict__ w1t, const float* __restrict__ b1,
          uint16_t* __restrict__ hb, int m0base, int crowOff)
{
  __shared__ __align__(16) char smem[32768];   // 4 waves x 8KB (16 rows x 512B)
  const int t = threadIdx.x;
  const int m0 = m0base + blockIdx.x * 32;
  const int lane = t & 63;
  const int wv = t >> 6;
  const int l15 = lane & 15;
  const int lg = lane >> 4;                    // 0..3
  const int* srcS = idx;
  const int* dstS = idx + NEDGES;
  const int* eidx = idx + 2*NEDGES;

  int eidxr[2];
  #pragma unroll
  for (int fr = 0; fr < 2; ++fr) eidxr[fr] = eidx[m0 + fr*16 + l15];

  // ---- preload all 8 iterations' (src,dst) — removes index chain from epilogue
  int sA[8], dA[8];
  #pragma unroll
  for (int it = 0; it < 8; ++it){
    int row2 = (it & 3)*4 + lg;
    int g = m0 + (it >> 2)*16 + row2;
    sA[it] = srcS[g];
    dA[it] = dstS[g];
  }

  const int pqoff = wv*128 + l15*4;
  ushort4 pA0, pA1, qA0, qA1;    // even iterations
  ushort4 pB0, pB1, qB0, qB1;    // odd iterations
  auto LDPQ = [&](int s, int d, ushort4& p0, ushort4& p1, ushort4& q0, ushort4& q1){
    const uint16_t* pb = PQb + (size_t)s*1024 + pqoff;
    const uint16_t* qb = PQb + (size_t)d*1024 + 512 + pqoff;
    p0 = *(const ushort4*)pb;  p1 = *(const ushort4*)(pb + 64);
    q0 = *(const ushort4*)qb;  q1 = *(const ushort4*)(qb + 64);
  };
  LDPQ(sA[0], dA[0], pA0, pA1, qA0, qA1);     // hides under MFMA phase
  LDPQ(sA[1], dA[1], pB0, pB1, qB0, qB1);

  f32x4 acc[2][8] = {};
  #pragma unroll
  for (int ks = 0; ks < 2; ++ks){
    bf16x8 bF[8];
    #pragma unroll
    for (int fc = 0; fc < 8; ++fc){
      int n = wv*128 + fc*16 + l15;
      bF[fc] = *(const bf16x8*)(w1t + (size_t)n*KFEAT + 2*HID + ks*32 + lg*8);
    }
    #pragma unroll
    for (int fr = 0; fr < 2; ++fr){
      bf16x8 av = *(const bf16x8*)(eab + (size_t)eidxr[fr]*EDIM + ks*32 + lg*8);
      #pragma unroll
      for (int fc = 0; fc < 8; ++fc)
        acc[fr][fc] = __builtin_amdgcn_mfma_f32_16x16x32_bf16(av, bF[fc], acc[fr][fc], 0, 0, 0);
    }
  }

  // ---- epilogue: slab transpose + depth-2 pipelined P/Q + mish + store
  char* slab = smem + wv*8192;
  const float4 b1v0 = *(const float4*)(b1 + wv*128 + l15*4);
  const float4 b1v1 = *(const float4*)(b1 + wv*128 + 64 + l15*4);
  #pragma unroll
  for (int fr = 0; fr < 2; ++fr){
    #pragma unroll
    for (int fc = 0; fc < 8; ++fc){
      #pragma unroll
      for (int r = 0; r < 4; ++r){
        int row = lg*4 + r;                    // row>>2 == lg
        int cb = ((fc*16 + l15)*4) ^ ((lg & 1) << 6);
        *(float*)(slab + row*512 + cb) = acc[fr][fc][r];
      }
    }
    asm volatile("s_waitcnt lgkmcnt(0)" ::: "memory");
    __builtin_amdgcn_sched_barrier(0);
    #pragma unroll
    for (int i = 0; i < 4; ++i){
      const int it = fr*4 + i;
      // compile-time buffer select (loop fully unrolled)
      ushort4& cp0 = (it & 1) ? pB0 : pA0;
      ushort4& cp1 = (it & 1) ? pB1 : pA1;
      ushort4& cq0 = (it & 1) ? qB0 : qA0;
      ushort4& cq1 = (it & 1) ? qB1 : qA1;
      int row = i*4 + lg;                      // row>>2 == i
      int grow = m0 + fr*16 + row;
      float4 v0 = *(const float4*)(slab + row*512 + ((l15*16) ^ ((i & 1) << 6)));
      float4 v1 = *(const float4*)(slab + row*512 + ((256 + l15*16) ^ ((i & 1) << 6)));
      ushort4 h0, h1;
      h0.x = f2bf(mishf(v0.x + bf2f(cp0.x) + bf2f(cq0.x) + b1v0.x));
      h0.y = f2bf(mishf(v0.y + bf2f(cp0.y) + bf2f(cq0.y) + b1v0.y));
      h0.z = f2bf(mishf(v0.z + bf2f(cp0.z) + bf2f(cq0.z) + b1v0.z));
      h0.w = f2bf(mishf(v0.w + bf2f(cp0.w) + bf2f(cq0.w) + b1v0.w));
      h1.x = f2bf(mishf(v1.x + bf2f(cp1.x) + bf2f(cq1.x) + b1v1.x));
      h1.y = f2bf(mishf(v1.y + bf2f(cp1.y) + bf2f(cq1.y) + b1v1.y));
      h1.z = f2bf(mishf(v1.z + bf2f(cp1.z) + bf2f(cq1.z) + b1v1.z));
      h1.w = f2bf(mishf(v1.w + bf2f(cp1.w) + bf2f(cq1.w) + b1v1.w));
      size_t hrow = (size_t)(grow - crowOff) * HID + wv*128;
      *(ushort4*)(hb + hrow + l15*4) = h0;
      *(ushort4*)(hb + hrow + 64 + l15*4) = h1;
      if (it + 2 < 8)                          // refill same parity buffer, depth 2
        LDPQ(sA[it+2], dA[it+2], cp0, cp1, cq0, cq1);
    }
    asm volatile("s_waitcnt lgkmcnt(0)" ::: "memory");
    __builtin_amdgcn_sched_barrier(0);
  }
}

// ---- CSR gather-reduce with deferred bias+mish; final chunk also writes aggb ----
__global__ __launch_bounds__(128)
void gather_agg(const uint16_t* __restrict__ msg, const int* __restrict__ rp,
                const float* __restrict__ b2, float* __restrict__ agg,
                uint16_t* __restrict__ aggb, int e0, int e1, int fin){
  const int n = blockIdx.x;
  int lo = rp[n], hi = rp[n+1];
  if (lo < e0) lo = e0;
  if (hi > e1) hi = e1;
  if (!fin && lo >= hi) return;
  const int t = threadIdx.x;
  const float4 bv = ((const float4*)b2)[t];
  float4 a = {0.f, 0.f, 0.f, 0.f};
  for (int e = lo; e < hi; ++e){
    ushort4 m = ((const ushort4*)(msg + (size_t)(e - e0) * HID))[t];
    a.x += mishf(bf2f(m.x) + bv.x);
    a.y += mishf(bf2f(m.y) + bv.y);
    a.z += mishf(bf2f(m.z) + bv.z);
    a.w += mishf(bf2f(m.w) + bv.w);
  }
  float4* ap = ((float4*)(agg + (size_t)n * HID)) + t;
  float4 c = *ap;
  c.x += a.x; c.y += a.y; c.z += a.z; c.w += a.w;
  if (lo < hi) *ap = c;
  if (fin){
    ushort4 o;
    o.x = f2bf(c.x); o.y = f2bf(c.y); o.z = f2bf(c.z); o.w = f2bf(c.w);
    ((ushort4*)(aggb + (size_t)n * HID))[t] = o;
  }
}

// ---------------- residual + LayerNorm ----------------
__global__ __launch_bounds__(128)
void resid_ln(const float* __restrict__ x, const float* __restrict__ ob,
              const float* __restrict__ gamma, const float* __restrict__ beta,
              float* __restrict__ y){
  const int row = blockIdx.x;
  const int t = threadIdx.x;
  const float4 xv = ((const float4*)(x + (size_t)row * HID))[t];
  const float4 ov = ((const float4*)(ob + (size_t)row * HID))[t];
  float4 s4;
  s4.x = xv.x + ov.x; s4.y = xv.y + ov.y; s4.z = xv.z + ov.z; s4.w = xv.w + ov.w;
  float s = s4.x + s4.y + s4.z + s4.w;
  float q = s4.x*s4.x + s4.y*s4.y + s4.z*s4.z + s4.w*s4.w;
  #pragma unroll
  for (int o = 32; o; o >>= 1){
    s += __shfl_xor(s, o, 64);
    q += __shfl_xor(q, o, 64);
  }
  __shared__ float ss[2], qq[2];
  if ((t & 63) == 0){ ss[t >> 6] = s; qq[t >> 6] = q; }
  __syncthreads();
  const float S = ss[0] + ss[1], Q = qq[0] + qq[1];
  const float mu = S * (1.0f / HID);
  const float var = Q * (1.0f / HID) - mu * mu;
  const float inv = rsqrtf(var + 1e-5f);
  const float4 g = ((const float4*)gamma)[t];
  const float4 b = ((const float4*)beta)[t];
  float4 o;
  o.x = (s4.x - mu) * inv * g.x + b.x;
  o.y = (s4.y - mu) * inv * g.y + b.y;
  o.z = (s4.z - mu) * inv * g.z + b.z;
  o.w = (s4.w - mu) * inv * g.w + b.w;
  ((float4*)(y + (size_t)row * HID))[t] = o;
}

extern "C" void kernel_launch(void* const* d_in, const int* in_sizes, int n_in,
                              void* d_out, int out_size, void* d_ws, size_t ws_size,
                              hipStream_t stream)
{
  const float* x    = (const float*)d_in[0];
  const int*   ei   = (const int*)d_in[1];
  const float* ea   = (const float*)d_in[2];
  const float* W1   = (const float*)d_in[3];
  const float* b1   = (const float*)d_in[4];
  const float* W2   = (const float*)d_in[5];
  const float* b2   = (const float*)d_in[6];
  const float* W3   = (const float*)d_in[7];
  const float* b3   = (const float*)d_in[8];
  const float* W4   = (const float*)d_in[9];
  const float* b4   = (const float*)d_in[10];
  const float* gmm  = (const float*)d_in[11];
  const float* bet  = (const float*)d_in[12];
  float* out = (float*)d_out;

  uint8_t* w = (uint8_t*)d_ws;
  size_t off = 0;
  auto alloc = [&](size_t bytes) -> void* {
    void* p = w + off;
    off += (bytes + 255) & ~(size_t)255;
    return p;
  };
  uint16_t* xb   = (uint16_t*)alloc((size_t)NNODES*HID*2);
  uint16_t* w1t  = (uint16_t*)alloc((size_t)HID*KFEAT*2);
  uint16_t* w2t  = (uint16_t*)alloc((size_t)HID*HID*2);
  uint16_t* w3t  = (uint16_t*)alloc((size_t)HID*1024*2);
  uint16_t* w4t  = (uint16_t*)alloc((size_t)HID*HID*2);
  uint16_t* PQb  = (uint16_t*)alloc((size_t)NNODES*1024*2);   // [n][1024]: P|Q
  float*    agg  = (float*)alloc((size_t)NNODES*HID*4);
  float*    outf = (float*)alloc((size_t)NNODES*HID*4);
  int*      srcN = (int*)alloc((size_t)NEDGES*4);
  int*      dstN = (int*)alloc((size_t)NEDGES*4);
  int*      idxS = (int*)alloc((size_t)NEDGES*4*3);  // [srcS | dstS | eidx]
  int*      cnt  = (int*)alloc((size_t)NNODES*4);
  int*      rp   = (int*)alloc((size_t)(NNODES+1)*4);
  int*      cur  = (int*)alloc((size_t)NNODES*4);
  int*      flag = (int*)alloc(256);
  int*      srcS = idxS;
  int*      dstS = idxS + NEDGES;
  int*      eidx = idxS + 2*NEDGES;

  // Aliases (lifetime-checked):
  // eab (41 MB)   aliases outf  — eab dead before GEMM4 writes outf.
  // aggb (20.5MB) aliases PQb[0:half]  — PQb dead after last eh_k; aggb written after.
  // ub   (20.5MB) aliases PQb[half:]   — written by GEMM3 after aggb exists; disjoint.
  uint16_t* eab  = (uint16_t*)outf;
  uint16_t* aggb = PQb;
  uint16_t* ub   = PQb + (size_t)NNODES*HID;

  size_t remain = (ws_size > off) ? ws_size - off : 0;
  size_t maxChunk = remain / ((size_t)HID*2*2);    // hb + msgb
  long long chunkE = (long long)(maxChunk & ~(size_t)1023);  // %1024 -> nty%8==0
  if (chunkE > NEDGES) chunkE = NEDGES;
  if (chunkE < 1024) chunkE = 1024;
  uint16_t* hb   = (uint16_t*)alloc((size_t)chunkE*HID*2);
  uint16_t* msgb = (uint16_t*)alloc((size_t)chunkE*HID*2);

  hipMemsetAsync(agg, 0, (size_t)NNODES*HID*4, stream);
  hipMemsetAsync(cnt, 0, (size_t)NNODES*4, stream);
  hipMemsetAsync(flag, 0, 4, stream);

  detect_idx<<<64, 256, 0, stream>>>(ei, flag);
  norm_idx<<<(NEDGES+255)/256, 256, 0, stream>>>(ei, flag, srcN, dstN);
  hist_k<<<(NEDGES+255)/256, 256, 0, stream>>>(dstN, cnt);
  scan_k<<<1, 256, 0, stream>>>(cnt, rp, cur);
  permute_k<<<(NEDGES+255)/256, 256, 0, stream>>>(srcN, dstN, cur, srcS, eidx);
  fill_dstS<<<NNODES, 64, 0, stream>>>(rp, dstS);

  cast_bf16_vec<<<(NNODES*HID/4+255)/256, 256, 0, stream>>>((const float4*)x, (ushort4*)xb, NNODES*HID/4);
  cast_bf16_vec<<<(NEDGES*EDIM/4+255)/256, 256, 0, stream>>>((const float4*)ea, (ushort4*)eab, NEDGES*EDIM/4);

  transpose_cast<<<dim3((KFEAT+255)/256, HID), 256, 0, stream>>>(W1, w1t, KFEAT, HID);
  transpose_cast<<<dim3((HID+255)/256,   HID), 256, 0, stream>>>(W2, w2t, HID, HID);
  transpose_cast<<<dim3((1024+255)/256,  HID), 256, 0, stream>>>(W3, w3t, 1024, HID);
  transpose_cast<<<dim3((HID+255)/256,   HID), 256, 0, stream>>>(W4, w4t, HID, HID);

  // Fused P|Q = x @ [W1a | W1b]  (N=1024, bf16 output, no bias/act)
  // nty=160 (%8==0 -> XCD grouping; padded tiles clamp rows, write-guarded)
  dim3 gpq(1024/128, 160);
  gemm_k<AM_DIR, EP_BF16L, HID, 1><<<gpq, 256, 0, stream>>>(
      xb, nullptr, w1t, b1, PQb, nullptr, KFEAT, 1024, 0, NNODES, 0);

  for (long long e0 = 0; e0 < NEDGES; e0 += chunkE){
    int ce = (int)((NEDGES - e0 < chunkE) ? (NEDGES - e0) : chunkE);
    int fin = (e0 + chunkE >= NEDGES) ? 1 : 0;
    // EH: h = mish(ea@W1c + P[src] + Q[dst] + b1) -> hb (chunk-local)
    eh_k<<<(ce+31)/32, 256, 0, stream>>>(eab, PQb, idxS, w1t, b1, hb, (int)e0, (int)e0);
    // GEMM2: hb @ W2 -> raw bf16 msgb (bias+mish deferred to gather)
    dim3 g2(HID/128, (ce+127)/128);
    gemm_k<AM_DIR, EP_RAW, HID, 0><<<g2, 256, 0, stream>>>(
        hb, nullptr, w2t, b2, msgb, nullptr, HID, HID, 0, ce, 0);
    // CSR gather-reduce: agg[n] += mish(msg + b2); final chunk also emits aggb
    gather_agg<<<NNODES, 128, 0, stream>>>(msgb, rp, b2, agg, aggb,
                                           (int)e0, (int)(e0+ce), fin);
  }

  dim3 g3(HID/128, 160);
  gemm_k<AM_NODE, EP_BF16, 1024, 0><<<g3, 256, 0, stream>>>(
      xb, aggb, w3t, b3, ub, nullptr, 1024, HID, 0, NNODES, 0);
  gemm_k<AM_DIR, EP_F32, HID, 0><<<g3, 256, 0, stream>>>(
      ub, nullptr, w4t, b4, nullptr, outf, HID, HID, 0, NNODES, 0);

  resid_ln<<<NNODES, 128, 0, stream>>>(x, outf, gmm, bet, out);
}

// Round 14
// 905.546 us; speedup vs baseline: 1.0105x; 1.0084x over previous
//
#include <hip/hip_runtime.h>
#include <cstdint>
#include <cstddef>

#define NNODES 20000
#define NEDGES 320000
#define HID 512
#define EDIM 64
#define KFEAT (2*HID + EDIM)   // 1088
#define SB 80
#define SSEG 250               // SB*SSEG == NNODES

typedef __bf16 bf16x8 __attribute__((ext_vector_type(8)));
typedef short short8 __attribute__((ext_vector_type(8)));
typedef float f32x4 __attribute__((ext_vector_type(4)));

#define AM_NODE 1
#define AM_DIR  2
#define EP_BF16    0   // +bias, mish, bf16 store
#define EP_F32     2   // +bias, raw f32 store
#define EP_BF16L   3   // no bias, no mish, bf16 store
#define EP_RAW     5   // raw f2bf(acc) store (bias+mish deferred to consumer)

__device__ __forceinline__ uint16_t f2bf(float f){
  uint32_t u = __float_as_uint(f);
  u += 0x7FFFu + ((u >> 16) & 1u);
  return (uint16_t)(u >> 16);
}
__device__ __forceinline__ float bf2f(uint16_t h){
  return __uint_as_float((uint32_t)h << 16);
}
// mish(x) = x * tanh(softplus(x)) = x * (e^2+2e)/(e^2+2e+2), e = exp(x)
__device__ __forceinline__ float mishf(float v){
  float e = __expf(fminf(v, 18.f));
  float n = e * (e + 2.f);
  return v * __fdividef(n, n + 2.f);
}
__device__ __forceinline__ void gl_lds16(const void* g, void* l){
  __builtin_amdgcn_global_load_lds(
      (const __attribute__((address_space(1))) uint32_t*)g,
      (__attribute__((address_space(3))) uint32_t*)l, 16, 0, 0);
}

// ---------------- index dtype detect / normalize ----------------
__global__ void detect_idx(const int* __restrict__ e, int* __restrict__ flag){
  int i = blockIdx.x * 256 + threadIdx.x;   // probe first 16384 pairs
  if (e[2*i + 1] != 0) atomicOr(flag, 1);   // flag=1 -> int32 layout
}
__global__ void norm_idx(const int* __restrict__ e, const int* __restrict__ flag,
                         int* __restrict__ s, int* __restrict__ d){
  int i = blockIdx.x * 256 + threadIdx.x;
  if (i >= NEDGES) return;
  int sv, dv;
  if (*flag){ sv = e[i];     dv = e[NEDGES + i]; }
  else      { sv = e[2*i];   dv = e[2*NEDGES + 2*i]; }   // int64 lo words
  sv = sv < 0 ? 0 : (sv > NNODES-1 ? NNODES-1 : sv);
  dv = dv < 0 ? 0 : (dv > NNODES-1 ? NNODES-1 : dv);
  s[i] = sv; d[i] = dv;
}

// ---------------- counting sort by dst (single permutation) ----------------
__global__ void hist_k(const int* __restrict__ d, int* __restrict__ cnt){
  int i = blockIdx.x * 256 + threadIdx.x;
  if (i < NEDGES) atomicAdd(&cnt[d[i]], 1);
}
// Multi-block exclusive scan over cnt[NNODES]: scan1 (per-block) -> scan2 (block
// offsets, serial over 80) -> scan3 (apply offsets, emit rp & cur).
__global__ __launch_bounds__(256)
void scan1(const int* __restrict__ cnt, int* __restrict__ rp, int* __restrict__ bsum){
  __shared__ int sh[256];
  const int b = blockIdx.x, t = threadIdx.x;
  int v = (t < SSEG) ? cnt[b*SSEG + t] : 0;
  sh[t] = v; __syncthreads();
  for (int o = 1; o < 256; o <<= 1){
    int u = (t >= o) ? sh[t-o] : 0;
    __syncthreads();
    sh[t] += u;
    __syncthreads();
  }
  if (t < SSEG) rp[b*SSEG + t] = sh[t] - v;   // exclusive local prefix
  if (t == 255) bsum[b] = sh[255];
}
__global__ void scan2(const int* __restrict__ bsum, int* __restrict__ boff,
                      int* __restrict__ rpN){
  if (threadIdx.x == 0){
    int acc = 0;
    for (int i = 0; i < SB; ++i){ boff[i] = acc; acc += bsum[i]; }
    *rpN = acc;
  }
}
__global__ __launch_bounds__(256)
void scan3(int* __restrict__ rp, const int* __restrict__ boff, int* __restrict__ cur){
  const int b = blockIdx.x, t = threadIdx.x;
  if (t < SSEG){
    int i = b*SSEG + t;
    int v = rp[i] + boff[b];
    rp[i] = v; cur[i] = v;
  }
}
// ONE permutation: sorted position p gets src id AND original edge id.
__global__ void permute_k(const int* __restrict__ srcN, const int* __restrict__ dstN,
                          int* __restrict__ cur, int* __restrict__ srcS,
                          int* __restrict__ eidx){
  int i = blockIdx.x * 256 + threadIdx.x;
  if (i < NEDGES){
    int d = dstN[i];
    int p = atomicAdd(&cur[d], 1);
    srcS[p] = srcN[i];
    eidx[p] = i;
  }
}
__global__ void fill_dstS(const int* __restrict__ rp, int* __restrict__ dstS){
  int n = blockIdx.x;
  int lo = rp[n], hi = rp[n+1];
  for (int e = lo + threadIdx.x; e < hi; e += 64) dstS[e] = n;
}

// ---------------- casts ----------------
__global__ void cast_bf16_vec(const float4* __restrict__ in, ushort4* __restrict__ out, int n4){
  int i = blockIdx.x * 256 + threadIdx.x;
  if (i < n4){
    float4 v = in[i];
    ushort4 o; o.x = f2bf(v.x); o.y = f2bf(v.y); o.z = f2bf(v.z); o.w = f2bf(v.w);
    out[i] = o;
  }
}
// Tiled transpose+cast: WT[n*K+k] = bf16(W[k*N+n]); coalesced on both sides.
__global__ __launch_bounds__(256)
void transpose_cast(const float* __restrict__ W, uint16_t* __restrict__ WT, int K, int N){
  __shared__ uint16_t tile[64][65];
  const int k0 = blockIdx.x * 64;
  const int n0 = blockIdx.y * 64;
  const int c = threadIdx.x & 63;
  const int r0 = threadIdx.x >> 6;    // 0..3
  #pragma unroll
  for (int rr = 0; rr < 64; rr += 4){
    int k = k0 + rr + r0, n = n0 + c;
    if (k < K && n < N) tile[rr + r0][c] = f2bf(W[(size_t)k*N + n]);
  }
  __syncthreads();
  #pragma unroll
  for (int rr = 0; rr < 64; rr += 4){
    int n = n0 + rr + r0, k = k0 + c;
    if (n < N && k < K) WT[(size_t)n*K + k] = tile[c][rr + r0];
  }
}

// ---------------- fused MFMA GEMM (128x128 tile, BK=64, 4 waves) ----------------
// Block remap: when nty%8==0, group row panels per XCD (flat%8 == XCD round-robin):
//   xcd = flat&7, i = flat>>3, by = xcd*(nty/8) + i/ntx, bx = i%ntx
// AM_NODE: row gm = [xb[gm] | aggb[gm]]  (K = 1024)
// AM_DIR : row-major A0, stride KTOT
// BPQ=1  : B^T row n -> w1t + (n&511)*bstr + (n>>9)*512  (fused P|Q, N=1024)
template<int AMODE, int EPI, int KTOT, int BPQ>
__global__ __launch_bounds__(256, 2)
void gemm_k(const uint16_t* __restrict__ A0, const uint16_t* __restrict__ A1,
            const uint16_t* __restrict__ BT, const float* __restrict__ bias,
            uint16_t* __restrict__ Cb, float* __restrict__ Cf,
            int bstr, int cstr, int m0base, int M, int crowOff)
{
  __shared__ __align__(16) char smem[32768];
  char* As = smem;
  char* Bs = smem + 16384;
  const int t = threadIdx.x;
  const int ntx = gridDim.x, nty = gridDim.y;
  int bx = blockIdx.x, by = blockIdx.y;
  if ((nty & 7) == 0){
    int flat = by * ntx + bx;
    int xcd = flat & 7;
    int i = flat >> 3;
    by = xcd * (nty >> 3) + i / ntx;
    bx = i % ntx;
  }
  const int m0 = m0base + by * 128;
  const int n0 = bx * 128;
  const int srow = t >> 3;
  const int c8   = t & 7;
  const int scol = ((c8 ^ (srow & 7)) << 3);
  const int ldst = srow * 128 + c8 * 16;

  const uint16_t* as0[4]; const uint16_t* as1[4];
  #pragma unroll
  for (int i = 0; i < 4; ++i){
    int gm = m0 + srow + 32*i;
    if (gm > M - 1) gm = M - 1;
    if (AMODE == AM_NODE){
      as0[i] = A0 + (size_t)gm * HID;
      as1[i] = A1 + (size_t)gm * HID;
    } else {
      as0[i] = A0 + (size_t)gm * KTOT;
      as1[i] = A0;
    }
  }
  const uint16_t* brow[4];
  #pragma unroll
  for (int i = 0; i < 4; ++i){
    int nr = n0 + srow + 32*i;
    if (BPQ) brow[i] = BT + (size_t)(nr & (HID-1))*bstr + (nr >> 9)*HID;
    else     brow[i] = BT + (size_t)nr*bstr;
  }

  const int lane = t & 63;
  const int wv = t >> 6;
  const int wm = (wv >> 1) * 64;
  const int wn = (wv & 1) * 64;
  const int l15 = lane & 15;
  const int lk16 = (lane >> 4) << 4;
  const int swz = (l15 & 7) << 4;

  f32x4 acc[4][4] = {};

  const int NK = KTOT / 64;
  for (int kk = 0; kk < NK; ++kk){
    const int k0 = kk * 64;
    #pragma unroll
    for (int i = 0; i < 4; ++i){
      const uint16_t* g;
      if (AMODE == AM_NODE){
        g = (k0 < HID) ? as0[i] + (k0 + scol) : as1[i] + (k0 - HID + scol);
      } else {
        g = as0[i] + (k0 + scol);
      }
      gl_lds16(g, As + i*4096 + ldst);
    }
    #pragma unroll
    for (int i = 0; i < 4; ++i)
      gl_lds16(brow[i] + (k0 + scol), Bs + i*4096 + ldst);
    __syncthreads();
    #pragma unroll
    for (int ks = 0; ks < 2; ++ks){
      bf16x8 af[4], bfr[4];
      #pragma unroll
      for (int i = 0; i < 4; ++i){
        const int ar = wm + i*16 + l15;
        af[i] = *(const bf16x8*)(As + ar*128 + ((ks*64 + lk16) ^ swz));
      }
      #pragma unroll
      for (int j = 0; j < 4; ++j){
        const int br = wn + j*16 + l15;
        bfr[j] = *(const bf16x8*)(Bs + br*128 + ((ks*64 + lk16) ^ swz));
      }
      #pragma unroll
      for (int i = 0; i < 4; ++i)
        #pragma unroll
        for (int j = 0; j < 4; ++j)
          acc[i][j] = __builtin_amdgcn_mfma_f32_16x16x32_bf16(af[i], bfr[j], acc[i][j], 0, 0, 0);
    }
    __syncthreads();
  }

  #pragma unroll
  for (int i = 0; i < 4; ++i){
    const int rb = wm + i*16 + ((lane >> 4) << 2);
    #pragma unroll
    for (int j = 0; j < 4; ++j){
      const int gcol = n0 + wn + j*16 + l15;
      const float bv = (EPI == EP_BF16L || EPI == EP_RAW) ? 0.f : bias[gcol];
      #pragma unroll
      for (int r = 0; r < 4; ++r){
        const int grow = m0 + rb + r;
        if (grow < M){
          float v = acc[i][j][r] + bv;
          if (EPI == EP_BF16){
            Cb[(size_t)(grow - crowOff) * cstr + gcol] = f2bf(mishf(v));
          } else if (EPI == EP_BF16L || EPI == EP_RAW){
            Cb[(size_t)(grow - crowOff) * cstr + gcol] = f2bf(v);
          } else {
            Cf[(size_t)grow * cstr + gcol] = v;
          }
        }
      }
    }
  }
}

// ---------------- EH: h = mish(ea@W1c + P[src] + Q[dst] + b1) ----------------
// 256 threads = 4 waves; block = 32 edges x 512 cols; wave wv owns cols [wv*128, +128).
// Indices preloaded; P/Q double-buffered depth 2 (it=0,1 issued before MFMA phase).
__global__ __launch_bounds__(256, 4)
void eh_k(const uint16_t* __restrict__ eab, const uint16_t* __restrict__ PQb,
          const int* __restrict__ idx,
          const uint16_t* __restrict__ w1t, const float* __restrict__ b1,
          uint16_t* __restrict__ hb, int m0base, int crowOff)
{
  __shared__ __align__(16) char smem[32768];   // 4 waves x 8KB (16 rows x 512B)
  const int t = threadIdx.x;
  const int m0 = m0base + blockIdx.x * 32;
  const int lane = t & 63;
  const int wv = t >> 6;
  const int l15 = lane & 15;
  const int lg = lane >> 4;                    // 0..3
  const int* srcS = idx;
  const int* dstS = idx + NEDGES;
  const int* eidx = idx + 2*NEDGES;

  int eidxr[2];
  #pragma unroll
  for (int fr = 0; fr < 2; ++fr) eidxr[fr] = eidx[m0 + fr*16 + l15];

  int sA[8], dA[8];
  #pragma unroll
  for (int it = 0; it < 8; ++it){
    int row2 = (it & 3)*4 + lg;
    int g = m0 + (it >> 2)*16 + row2;
    sA[it] = srcS[g];
    dA[it] = dstS[g];
  }

  const int pqoff = wv*128 + l15*4;
  ushort4 pA0, pA1, qA0, qA1;    // even iterations
  ushort4 pB0, pB1, qB0, qB1;    // odd iterations
  auto LDPQ = [&](int s, int d, ushort4& p0, ushort4& p1, ushort4& q0, ushort4& q1){
    const uint16_t* pb = PQb + (size_t)s*1024 + pqoff;
    const uint16_t* qb = PQb + (size_t)d*1024 + 512 + pqoff;
    p0 = *(const ushort4*)pb;  p1 = *(const ushort4*)(pb + 64);
    q0 = *(const ushort4*)qb;  q1 = *(const ushort4*)(qb + 64);
  };
  LDPQ(sA[0], dA[0], pA0, pA1, qA0, qA1);     // hides under MFMA phase
  LDPQ(sA[1], dA[1], pB0, pB1, qB0, qB1);

  f32x4 acc[2][8] = {};
  #pragma unroll
  for (int ks = 0; ks < 2; ++ks){
    bf16x8 bF[8];
    #pragma unroll
    for (int fc = 0; fc < 8; ++fc){
      int n = wv*128 + fc*16 + l15;
      bF[fc] = *(const bf16x8*)(w1t + (size_t)n*KFEAT + 2*HID + ks*32 + lg*8);
    }
    #pragma unroll
    for (int fr = 0; fr < 2; ++fr){
      bf16x8 av = *(const bf16x8*)(eab + (size_t)eidxr[fr]*EDIM + ks*32 + lg*8);
      #pragma unroll
      for (int fc = 0; fc < 8; ++fc)
        acc[fr][fc] = __builtin_amdgcn_mfma_f32_16x16x32_bf16(av, bF[fc], acc[fr][fc], 0, 0, 0);
    }
  }

  // ---- epilogue: slab transpose + depth-2 pipelined P/Q + mish + store
  char* slab = smem + wv*8192;
  const float4 b1v0 = *(const float4*)(b1 + wv*128 + l15*4);
  const float4 b1v1 = *(const float4*)(b1 + wv*128 + 64 + l15*4);
  #pragma unroll
  for (int fr = 0; fr < 2; ++fr){
    #pragma unroll
    for (int fc = 0; fc < 8; ++fc){
      #pragma unroll
      for (int r = 0; r < 4; ++r){
        int row = lg*4 + r;                    // row>>2 == lg
        int cb = ((fc*16 + l15)*4) ^ ((lg & 1) << 6);
        *(float*)(slab + row*512 + cb) = acc[fr][fc][r];
      }
    }
    asm volatile("s_waitcnt lgkmcnt(0)" ::: "memory");
    __builtin_amdgcn_sched_barrier(0);
    #pragma unroll
    for (int i = 0; i < 4; ++i){
      const int it = fr*4 + i;
      ushort4& cp0 = (it & 1) ? pB0 : pA0;
      ushort4& cp1 = (it & 1) ? pB1 : pA1;
      ushort4& cq0 = (it & 1) ? qB0 : qA0;
      ushort4& cq1 = (it & 1) ? qB1 : qA1;
      int row = i*4 + lg;                      // row>>2 == i
      int grow = m0 + fr*16 + row;
      float4 v0 = *(const float4*)(slab + row*512 + ((l15*16) ^ ((i & 1) << 6)));
      float4 v1 = *(const float4*)(slab + row*512 + ((256 + l15*16) ^ ((i & 1) << 6)));
      ushort4 h0, h1;
      h0.x = f2bf(mishf(v0.x + bf2f(cp0.x) + bf2f(cq0.x) + b1v0.x));
      h0.y = f2bf(mishf(v0.y + bf2f(cp0.y) + bf2f(cq0.y) + b1v0.y));
      h0.z = f2bf(mishf(v0.z + bf2f(cp0.z) + bf2f(cq0.z) + b1v0.z));
      h0.w = f2bf(mishf(v0.w + bf2f(cp0.w) + bf2f(cq0.w) + b1v0.w));
      h1.x = f2bf(mishf(v1.x + bf2f(cp1.x) + bf2f(cq1.x) + b1v1.x));
      h1.y = f2bf(mishf(v1.y + bf2f(cp1.y) + bf2f(cq1.y) + b1v1.y));
      h1.z = f2bf(mishf(v1.z + bf2f(cp1.z) + bf2f(cq1.z) + b1v1.z));
      h1.w = f2bf(mishf(v1.w + bf2f(cp1.w) + bf2f(cq1.w) + b1v1.w));
      size_t hrow = (size_t)(grow - crowOff) * HID + wv*128;
      *(ushort4*)(hb + hrow + l15*4) = h0;
      *(ushort4*)(hb + hrow + 64 + l15*4) = h1;
      if (it + 2 < 8)
        LDPQ(sA[it+2], dA[it+2], cp0, cp1, cq0, cq1);
    }
    asm volatile("s_waitcnt lgkmcnt(0)" ::: "memory");
    __builtin_amdgcn_sched_barrier(0);
  }
}

// ---- CSR gather-reduce with deferred bias+mish; final chunk also writes aggb ----
__global__ __launch_bounds__(128)
void gather_agg(const uint16_t* __restrict__ msg, const int* __restrict__ rp,
                const float* __restrict__ b2, float* __restrict__ agg,
                uint16_t* __restrict__ aggb, int e0, int e1, int fin){
  const int n = blockIdx.x;
  int lo = rp[n], hi = rp[n+1];
  if (lo < e0) lo = e0;
  if (hi > e1) hi = e1;
  if (!fin && lo >= hi) return;
  const int t = threadIdx.x;
  const float4 bv = ((const float4*)b2)[t];
  float4 a = {0.f, 0.f, 0.f, 0.f};
  for (int e = lo; e < hi; ++e){
    ushort4 m = ((const ushort4*)(msg + (size_t)(e - e0) * HID))[t];
    a.x += mishf(bf2f(m.x) + bv.x);
    a.y += mishf(bf2f(m.y) + bv.y);
    a.z += mishf(bf2f(m.z) + bv.z);
    a.w += mishf(bf2f(m.w) + bv.w);
  }
  float4* ap = ((float4*)(agg + (size_t)n * HID)) + t;
  float4 c = *ap;
  c.x += a.x; c.y += a.y; c.z += a.z; c.w += a.w;
  if (lo < hi) *ap = c;
  if (fin){
    ushort4 o;
    o.x = f2bf(c.x); o.y = f2bf(c.y); o.z = f2bf(c.z); o.w = f2bf(c.w);
    ((ushort4*)(aggb + (size_t)n * HID))[t] = o;
  }
}

// ---------------- residual + LayerNorm ----------------
__global__ __launch_bounds__(128)
void resid_ln(const float* __restrict__ x, const float* __restrict__ ob,
              const float* __restrict__ gamma, const float* __restrict__ beta,
              float* __restrict__ y){
  const int row = blockIdx.x;
  const int t = threadIdx.x;
  const float4 xv = ((const float4*)(x + (size_t)row * HID))[t];
  const float4 ov = ((const float4*)(ob + (size_t)row * HID))[t];
  float4 s4;
  s4.x = xv.x + ov.x; s4.y = xv.y + ov.y; s4.z = xv.z + ov.z; s4.w = xv.w + ov.w;
  float s = s4.x + s4.y + s4.z + s4.w;
  float q = s4.x*s4.x + s4.y*s4.y + s4.z*s4.z + s4.w*s4.w;
  #pragma unroll
  for (int o = 32; o; o >>= 1){
    s += __shfl_xor(s, o, 64);
    q += __shfl_xor(q, o, 64);
  }
  __shared__ float ss[2], qq[2];
  if ((t & 63) == 0){ ss[t >> 6] = s; qq[t >> 6] = q; }
  __syncthreads();
  const float S = ss[0] + ss[1], Q = qq[0] + qq[1];
  const float mu = S * (1.0f / HID);
  const float var = Q * (1.0f / HID) - mu * mu;
  const float inv = rsqrtf(var + 1e-5f);
  const float4 g = ((const float4*)gamma)[t];
  const float4 b = ((const float4*)beta)[t];
  float4 o;
  o.x = (s4.x - mu) * inv * g.x + b.x;
  o.y = (s4.y - mu) * inv * g.y + b.y;
  o.z = (s4.z - mu) * inv * g.z + b.z;
  o.w = (s4.w - mu) * inv * g.w + b.w;
  ((float4*)(y + (size_t)row * HID))[t] = o;
}

extern "C" void kernel_launch(void* const* d_in, const int* in_sizes, int n_in,
                              void* d_out, int out_size, void* d_ws, size_t ws_size,
                              hipStream_t stream)
{
  const float* x    = (const float*)d_in[0];
  const int*   ei   = (const int*)d_in[1];
  const float* ea   = (const float*)d_in[2];
  const float* W1   = (const float*)d_in[3];
  const float* b1   = (const float*)d_in[4];
  const float* W2   = (const float*)d_in[5];
  const float* b2   = (const float*)d_in[6];
  const float* W3   = (const float*)d_in[7];
  const float* b3   = (const float*)d_in[8];
  const float* W4   = (const float*)d_in[9];
  const float* b4   = (const float*)d_in[10];
  const float* gmm  = (const float*)d_in[11];
  const float* bet  = (const float*)d_in[12];
  float* out = (float*)d_out;

  uint8_t* w = (uint8_t*)d_ws;
  size_t off = 0;
  auto alloc = [&](size_t bytes) -> void* {
    void* p = w + off;
    off += (bytes + 255) & ~(size_t)255;
    return p;
  };
  uint16_t* xb   = (uint16_t*)alloc((size_t)NNODES*HID*2);
  uint16_t* w1t  = (uint16_t*)alloc((size_t)HID*KFEAT*2);
  uint16_t* w2t  = (uint16_t*)alloc((size_t)HID*HID*2);
  uint16_t* w3t  = (uint16_t*)alloc((size_t)HID*1024*2);
  uint16_t* w4t  = (uint16_t*)alloc((size_t)HID*HID*2);
  uint16_t* PQb  = (uint16_t*)alloc((size_t)NNODES*1024*2);   // [n][1024]: P|Q
  float*    agg  = (float*)alloc((size_t)NNODES*HID*4);
  float*    outf = (float*)alloc((size_t)NNODES*HID*4);
  int*      srcN = (int*)alloc((size_t)NEDGES*4);
  int*      dstN = (int*)alloc((size_t)NEDGES*4);
  int*      idxS = (int*)alloc((size_t)NEDGES*4*3);  // [srcS | dstS | eidx]
  int*      cnt  = (int*)alloc((size_t)NNODES*4);
  int*      rp   = (int*)alloc((size_t)(NNODES+1)*4);
  int*      cur  = (int*)alloc((size_t)NNODES*4);
  int*      bsum = (int*)alloc((size_t)SB*4);
  int*      boff = (int*)alloc((size_t)SB*4);
  int*      flag = (int*)alloc(256);
  int*      srcS = idxS;
  int*      dstS = idxS + NEDGES;
  int*      eidx = idxS + 2*NEDGES;

  // Aliases (lifetime-checked):
  // eab (41 MB)   aliases outf  — eab dead before GEMM4 writes outf.
  // aggb (20.5MB) aliases PQb[0:half]  — PQb dead after last eh_k; aggb written after.
  // ub   (20.5MB) aliases PQb[half:]   — written by GEMM3 after aggb exists; disjoint.
  uint16_t* eab  = (uint16_t*)outf;
  uint16_t* aggb = PQb;
  uint16_t* ub   = PQb + (size_t)NNODES*HID;

  size_t remain = (ws_size > off) ? ws_size - off : 0;
  size_t maxChunk = remain / ((size_t)HID*2*2);    // hb + msgb
  long long chunkE = (long long)(maxChunk & ~(size_t)1023);
  if (chunkE > 65536) chunkE = 65536;              // keep hb+msgb+PQb L3-resident
  if (chunkE < 1024) chunkE = 1024;
  uint16_t* hb   = (uint16_t*)alloc((size_t)chunkE*HID*2);
  uint16_t* msgb = (uint16_t*)alloc((size_t)chunkE*HID*2);

  hipMemsetAsync(agg, 0, (size_t)NNODES*HID*4, stream);
  hipMemsetAsync(cnt, 0, (size_t)NNODES*4, stream);
  hipMemsetAsync(flag, 0, 4, stream);

  detect_idx<<<64, 256, 0, stream>>>(ei, flag);
  norm_idx<<<(NEDGES+255)/256, 256, 0, stream>>>(ei, flag, srcN, dstN);
  hist_k<<<(NEDGES+255)/256, 256, 0, stream>>>(dstN, cnt);
  scan1<<<SB, 256, 0, stream>>>(cnt, rp, bsum);
  scan2<<<1, 64, 0, stream>>>(bsum, boff, rp + NNODES);
  scan3<<<SB, 256, 0, stream>>>(rp, boff, cur);
  permute_k<<<(NEDGES+255)/256, 256, 0, stream>>>(srcN, dstN, cur, srcS, eidx);
  fill_dstS<<<NNODES, 64, 0, stream>>>(rp, dstS);

  cast_bf16_vec<<<(NNODES*HID/4+255)/256, 256, 0, stream>>>((const float4*)x, (ushort4*)xb, NNODES*HID/4);
  cast_bf16_vec<<<(NEDGES*EDIM/4+255)/256, 256, 0, stream>>>((const float4*)ea, (ushort4*)eab, NEDGES*EDIM/4);

  transpose_cast<<<dim3((KFEAT+63)/64, (HID+63)/64), 256, 0, stream>>>(W1, w1t, KFEAT, HID);
  transpose_cast<<<dim3((HID+63)/64,  (HID+63)/64), 256, 0, stream>>>(W2, w2t, HID, HID);
  transpose_cast<<<dim3((1024+63)/64, (HID+63)/64), 256, 0, stream>>>(W3, w3t, 1024, HID);
  transpose_cast<<<dim3((HID+63)/64,  (HID+63)/64), 256, 0, stream>>>(W4, w4t, HID, HID);

  // Fused P|Q = x @ [W1a | W1b]  (N=1024, bf16 output, no bias/act)
  // nty=160 (%8==0 -> XCD grouping; padded tiles clamp rows, write-guarded)
  dim3 gpq(1024/128, 160);
  gemm_k<AM_DIR, EP_BF16L, HID, 1><<<gpq, 256, 0, stream>>>(
      xb, nullptr, w1t, b1, PQb, nullptr, KFEAT, 1024, 0, NNODES, 0);

  for (long long e0 = 0; e0 < NEDGES; e0 += chunkE){
    int ce = (int)((NEDGES - e0 < chunkE) ? (NEDGES - e0) : chunkE);
    int fin = (e0 + chunkE >= NEDGES) ? 1 : 0;
    // EH: h = mish(ea@W1c + P[src] + Q[dst] + b1) -> hb (chunk-local)
    eh_k<<<(ce+31)/32, 256, 0, stream>>>(eab, PQb, idxS, w1t, b1, hb, (int)e0, (int)e0);
    // GEMM2: hb @ W2 -> raw bf16 msgb (bias+mish deferred to gather)
    dim3 g2(HID/128, (ce+127)/128);
    gemm_k<AM_DIR, EP_RAW, HID, 0><<<g2, 256, 0, stream>>>(
        hb, nullptr, w2t, b2, msgb, nullptr, HID, HID, 0, ce, 0);
    // CSR gather-reduce: agg[n] += mish(msg + b2); final chunk also emits aggb
    gather_agg<<<NNODES, 128, 0, stream>>>(msgb, rp, b2, agg, aggb,
                                           (int)e0, (int)(e0+ce), fin);
  }

  dim3 g3(HID/128, 160);
  gemm_k<AM_NODE, EP_BF16, 1024, 0><<<g3, 256, 0, stream>>>(
      xb, aggb, w3t, b3, ub, nullptr, 1024, HID, 0, NNODES, 0);
  gemm_k<AM_DIR, EP_F32, HID, 0><<<g3, 256, 0, stream>>>(
      ub, nullptr, w4t, b4, nullptr, outf, HID, HID, 0, NNODES, 0);

  resid_ln<<<NNODES, 128, 0, stream>>>(x, outf, gmm, bet, out);
}

// Round 15
// 895.922 us; speedup vs baseline: 1.0214x; 1.0107x over previous
//
#include <hip/hip_runtime.h>
#include <cstdint>
#include <cstddef>

#define NNODES 20000
#define NEDGES 320000
#define HID 512
#define EDIM 64
#define KFEAT (2*HID + EDIM)   // 1088
#define SB 80
#define SSEG 250               // SB*SSEG == NNODES

typedef __bf16 bf16x8 __attribute__((ext_vector_type(8)));
typedef short short8 __attribute__((ext_vector_type(8)));
typedef float f32x4 __attribute__((ext_vector_type(4)));

#define AM_NODE 1
#define AM_DIR  2
#define EP_BF16    0   // +bias, mish, bf16 store
#define EP_F32     2   // +bias, raw f32 store
#define EP_BF16L   3   // no bias, no mish, bf16 store
#define EP_RAW     5   // raw f2bf(acc) store (bias+mish deferred to consumer)

__device__ __forceinline__ uint16_t f2bf(float f){
  uint32_t u = __float_as_uint(f);
  u += 0x7FFFu + ((u >> 16) & 1u);
  return (uint16_t)(u >> 16);
}
__device__ __forceinline__ float bf2f(uint16_t h){
  return __uint_as_float((uint32_t)h << 16);
}
// mish(x) = x * tanh(softplus(x)) = x * (e^2+2e)/(e^2+2e+2), e = exp(x)
__device__ __forceinline__ float mishf(float v){
  float e = __expf(fminf(v, 18.f));
  float n = e * (e + 2.f);
  return v * __fdividef(n, n + 2.f);
}
__device__ __forceinline__ void gl_lds16(const void* g, void* l){
  __builtin_amdgcn_global_load_lds(
      (const __attribute__((address_space(1))) uint32_t*)g,
      (__attribute__((address_space(3))) uint32_t*)l, 16, 0, 0);
}

// ---------------- index dtype detect / normalize ----------------
__global__ void detect_idx(const int* __restrict__ e, int* __restrict__ flag){
  int i = blockIdx.x * 256 + threadIdx.x;   // probe first 16384 pairs
  if (e[2*i + 1] != 0) atomicOr(flag, 1);   // flag=1 -> int32 layout
}
__global__ void norm_idx(const int* __restrict__ e, const int* __restrict__ flag,
                         int* __restrict__ s, int* __restrict__ d){
  int i = blockIdx.x * 256 + threadIdx.x;
  if (i >= NEDGES) return;
  int sv, dv;
  if (*flag){ sv = e[i];     dv = e[NEDGES + i]; }
  else      { sv = e[2*i];   dv = e[2*NEDGES + 2*i]; }   // int64 lo words
  sv = sv < 0 ? 0 : (sv > NNODES-1 ? NNODES-1 : sv);
  dv = dv < 0 ? 0 : (dv > NNODES-1 ? NNODES-1 : dv);
  s[i] = sv; d[i] = dv;
}

// ---------------- counting sort by dst (single permutation) ----------------
__global__ void hist_k(const int* __restrict__ d, int* __restrict__ cnt){
  int i = blockIdx.x * 256 + threadIdx.x;
  if (i < NEDGES) atomicAdd(&cnt[d[i]], 1);
}
// Multi-block exclusive scan over cnt[NNODES]: scan1 (per-block) -> scan2 (block
// offsets, serial over 80) -> scan3 (apply offsets, emit rp & cur).
__global__ __launch_bounds__(256)
void scan1(const int* __restrict__ cnt, int* __restrict__ rp, int* __restrict__ bsum){
  __shared__ int sh[256];
  const int b = blockIdx.x, t = threadIdx.x;
  int v = (t < SSEG) ? cnt[b*SSEG + t] : 0;
  sh[t] = v; __syncthreads();
  for (int o = 1; o < 256; o <<= 1){
    int u = (t >= o) ? sh[t-o] : 0;
    __syncthreads();
    sh[t] += u;
    __syncthreads();
  }
  if (t < SSEG) rp[b*SSEG + t] = sh[t] - v;   // exclusive local prefix
  if (t == 255) bsum[b] = sh[255];
}
__global__ void scan2(const int* __restrict__ bsum, int* __restrict__ boff,
                      int* __restrict__ rpN){
  if (threadIdx.x == 0){
    int acc = 0;
    for (int i = 0; i < SB; ++i){ boff[i] = acc; acc += bsum[i]; }
    *rpN = acc;
  }
}
__global__ __launch_bounds__(256)
void scan3(int* __restrict__ rp, const int* __restrict__ boff, int* __restrict__ cur){
  const int b = blockIdx.x, t = threadIdx.x;
  if (t < SSEG){
    int i = b*SSEG + t;
    int v = rp[i] + boff[b];
    rp[i] = v; cur[i] = v;
  }
}
// ONE permutation: sorted position p gets src id AND original edge id.
__global__ void permute_k(const int* __restrict__ srcN, const int* __restrict__ dstN,
                          int* __restrict__ cur, int* __restrict__ srcS,
                          int* __restrict__ eidx){
  int i = blockIdx.x * 256 + threadIdx.x;
  if (i < NEDGES){
    int d = dstN[i];
    int p = atomicAdd(&cur[d], 1);
    srcS[p] = srcN[i];
    eidx[p] = i;
  }
}
__global__ void fill_dstS(const int* __restrict__ rp, int* __restrict__ dstS){
  int n = blockIdx.x;
  int lo = rp[n], hi = rp[n+1];
  for (int e = lo + threadIdx.x; e < hi; e += 64) dstS[e] = n;
}

// ---------------- casts ----------------
__global__ void cast_bf16_vec(const float4* __restrict__ in, ushort4* __restrict__ out, int n4){
  int i = blockIdx.x * 256 + threadIdx.x;
  if (i < n4){
    float4 v = in[i];
    ushort4 o; o.x = f2bf(v.x); o.y = f2bf(v.y); o.z = f2bf(v.z); o.w = f2bf(v.w);
    out[i] = o;
  }
}
// Tiled transpose+cast: WT[n*K+k] = bf16(W[k*N+n]); coalesced on both sides.
__global__ __launch_bounds__(256)
void transpose_cast(const float* __restrict__ W, uint16_t* __restrict__ WT, int K, int N){
  __shared__ uint16_t tile[64][65];
  const int k0 = blockIdx.x * 64;
  const int n0 = blockIdx.y * 64;
  const int c = threadIdx.x & 63;
  const int r0 = threadIdx.x >> 6;    // 0..3
  #pragma unroll
  for (int rr = 0; rr < 64; rr += 4){
    int k = k0 + rr + r0, n = n0 + c;
    if (k < K && n < N) tile[rr + r0][c] = f2bf(W[(size_t)k*N + n]);
  }
  __syncthreads();
  #pragma unroll
  for (int rr = 0; rr < 64; rr += 4){
    int n = n0 + rr + r0, k = k0 + c;
    if (n < N && k < K) WT[(size_t)n*K + k] = tile[c][rr + r0];
  }
}

// ---------------- fused MFMA GEMM (128x128 tile, BK=64, 4 waves) ----------------
// Block remap: when nty%8==0, group row panels per XCD (flat%8 == XCD round-robin):
//   xcd = flat&7, i = flat>>3, by = xcd*(nty/8) + i/ntx, bx = i%ntx
// AM_NODE: row gm = [xb[gm] | aggb[gm]]  (K = 1024)
// AM_DIR : row-major A0, stride KTOT
// BPQ=1  : B^T row n -> w1t + (n&511)*bstr + (n>>9)*512  (fused P|Q, N=1024)
template<int AMODE, int EPI, int KTOT, int BPQ>
__global__ __launch_bounds__(256, 2)
void gemm_k(const uint16_t* __restrict__ A0, const uint16_t* __restrict__ A1,
            const uint16_t* __restrict__ BT, const float* __restrict__ bias,
            uint16_t* __restrict__ Cb, float* __restrict__ Cf,
            int bstr, int cstr, int m0base, int M, int crowOff)
{
  __shared__ __align__(16) char smem[32768];
  char* As = smem;
  char* Bs = smem + 16384;
  const int t = threadIdx.x;
  const int ntx = gridDim.x, nty = gridDim.y;
  int bx = blockIdx.x, by = blockIdx.y;
  if ((nty & 7) == 0){
    int flat = by * ntx + bx;
    int xcd = flat & 7;
    int i = flat >> 3;
    by = xcd * (nty >> 3) + i / ntx;
    bx = i % ntx;
  }
  const int m0 = m0base + by * 128;
  const int n0 = bx * 128;
  const int srow = t >> 3;
  const int c8   = t & 7;
  const int scol = ((c8 ^ (srow & 7)) << 3);
  const int ldst = srow * 128 + c8 * 16;

  const uint16_t* as0[4]; const uint16_t* as1[4];
  #pragma unroll
  for (int i = 0; i < 4; ++i){
    int gm = m0 + srow + 32*i;
    if (gm > M - 1) gm = M - 1;
    if (AMODE == AM_NODE){
      as0[i] = A0 + (size_t)gm * HID;
      as1[i] = A1 + (size_t)gm * HID;
    } else {
      as0[i] = A0 + (size_t)gm * KTOT;
      as1[i] = A0;
    }
  }
  const uint16_t* brow[4];
  #pragma unroll
  for (int i = 0; i < 4; ++i){
    int nr = n0 + srow + 32*i;
    if (BPQ) brow[i] = BT + (size_t)(nr & (HID-1))*bstr + (nr >> 9)*HID;
    else     brow[i] = BT + (size_t)nr*bstr;
  }

  const int lane = t & 63;
  const int wv = t >> 6;
  const int wm = (wv >> 1) * 64;
  const int wn = (wv & 1) * 64;
  const int l15 = lane & 15;
  const int lk16 = (lane >> 4) << 4;
  const int swz = (l15 & 7) << 4;

  f32x4 acc[4][4] = {};

  const int NK = KTOT / 64;
  for (int kk = 0; kk < NK; ++kk){
    const int k0 = kk * 64;
    #pragma unroll
    for (int i = 0; i < 4; ++i){
      const uint16_t* g;
      if (AMODE == AM_NODE){
        g = (k0 < HID) ? as0[i] + (k0 + scol) : as1[i] + (k0 - HID + scol);
      } else {
        g = as0[i] + (k0 + scol);
      }
      gl_lds16(g, As + i*4096 + ldst);
    }
    #pragma unroll
    for (int i = 0; i < 4; ++i)
      gl_lds16(brow[i] + (k0 + scol), Bs + i*4096 + ldst);
    __syncthreads();
    #pragma unroll
    for (int ks = 0; ks < 2; ++ks){
      bf16x8 af[4], bfr[4];
      #pragma unroll
      for (int i = 0; i < 4; ++i){
        const int ar = wm + i*16 + l15;
        af[i] = *(const bf16x8*)(As + ar*128 + ((ks*64 + lk16) ^ swz));
      }
      #pragma unroll
      for (int j = 0; j < 4; ++j){
        const int br = wn + j*16 + l15;
        bfr[j] = *(const bf16x8*)(Bs + br*128 + ((ks*64 + lk16) ^ swz));
      }
      #pragma unroll
      for (int i = 0; i < 4; ++i)
        #pragma unroll
        for (int j = 0; j < 4; ++j)
          acc[i][j] = __builtin_amdgcn_mfma_f32_16x16x32_bf16(af[i], bfr[j], acc[i][j], 0, 0, 0);
    }
    __syncthreads();
  }

  #pragma unroll
  for (int i = 0; i < 4; ++i){
    const int rb = wm + i*16 + ((lane >> 4) << 2);
    #pragma unroll
    for (int j = 0; j < 4; ++j){
      const int gcol = n0 + wn + j*16 + l15;
      const float bv = (EPI == EP_BF16L || EPI == EP_RAW) ? 0.f : bias[gcol];
      #pragma unroll
      for (int r = 0; r < 4; ++r){
        const int grow = m0 + rb + r;
        if (grow < M){
          float v = acc[i][j][r] + bv;
          if (EPI == EP_BF16){
            Cb[(size_t)(grow - crowOff) * cstr + gcol] = f2bf(mishf(v));
          } else if (EPI == EP_BF16L || EPI == EP_RAW){
            Cb[(size_t)(grow - crowOff) * cstr + gcol] = f2bf(v);
          } else {
            Cf[(size_t)grow * cstr + gcol] = v;
          }
        }
      }
    }
  }
}

// ---------------- EH: h = mish(ea@W1c + P[src] + Q[dst] + b1) ----------------
// 256 threads = 4 waves; block = 32 edges x 512 cols; wave wv owns cols [wv*128, +128).
// Indices preloaded; P/Q double-buffered depth 2 (it=0,1 issued before MFMA phase).
__global__ __launch_bounds__(256, 4)
void eh_k(const uint16_t* __restrict__ eab, const uint16_t* __restrict__ PQb,
          const int* __restrict__ idx,
          const uint16_t* __restrict__ w1t, const float* __restrict__ b1,
          uint16_t* __restrict__ hb, int m0base, int crowOff)
{
  __shared__ __align__(16) char smem[32768];   // 4 waves x 8KB (16 rows x 512B)
  const int t = threadIdx.x;
  const int m0 = m0base + blockIdx.x * 32;
  const int lane = t & 63;
  const int wv = t >> 6;
  const int l15 = lane & 15;
  const int lg = lane >> 4;                    // 0..3
  const int* srcS = idx;
  const int* dstS = idx + NEDGES;
  const int* eidx = idx + 2*NEDGES;

  int eidxr[2];
  #pragma unroll
  for (int fr = 0; fr < 2; ++fr) eidxr[fr] = eidx[m0 + fr*16 + l15];

  int sA[8], dA[8];
  #pragma unroll
  for (int it = 0; it < 8; ++it){
    int row2 = (it & 3)*4 + lg;
    int g = m0 + (it >> 2)*16 + row2;
    sA[it] = srcS[g];
    dA[it] = dstS[g];
  }

  const int pqoff = wv*128 + l15*4;
  ushort4 pA0, pA1, qA0, qA1;    // even iterations
  ushort4 pB0, pB1, qB0, qB1;    // odd iterations
  auto LDPQ = [&](int s, int d, ushort4& p0, ushort4& p1, ushort4& q0, ushort4& q1){
    const uint16_t* pb = PQb + (size_t)s*1024 + pqoff;
    const uint16_t* qb = PQb + (size_t)d*1024 + 512 + pqoff;
    p0 = *(const ushort4*)pb;  p1 = *(const ushort4*)(pb + 64);
    q0 = *(const ushort4*)qb;  q1 = *(const ushort4*)(qb + 64);
  };
  LDPQ(sA[0], dA[0], pA0, pA1, qA0, qA1);     // hides under MFMA phase
  LDPQ(sA[1], dA[1], pB0, pB1, qB0, qB1);

  f32x4 acc[2][8] = {};
  #pragma unroll
  for (int ks = 0; ks < 2; ++ks){
    bf16x8 bF[8];
    #pragma unroll
    for (int fc = 0; fc < 8; ++fc){
      int n = wv*128 + fc*16 + l15;
      bF[fc] = *(const bf16x8*)(w1t + (size_t)n*KFEAT + 2*HID + ks*32 + lg*8);
    }
    #pragma unroll
    for (int fr = 0; fr < 2; ++fr){
      bf16x8 av = *(const bf16x8*)(eab + (size_t)eidxr[fr]*EDIM + ks*32 + lg*8);
      #pragma unroll
      for (int fc = 0; fc < 8; ++fc)
        acc[fr][fc] = __builtin_amdgcn_mfma_f32_16x16x32_bf16(av, bF[fc], acc[fr][fc], 0, 0, 0);
    }
  }

  // ---- epilogue: slab transpose + depth-2 pipelined P/Q + mish + store
  char* slab = smem + wv*8192;
  const float4 b1v0 = *(const float4*)(b1 + wv*128 + l15*4);
  const float4 b1v1 = *(const float4*)(b1 + wv*128 + 64 + l15*4);
  #pragma unroll
  for (int fr = 0; fr < 2; ++fr){
    #pragma unroll
    for (int fc = 0; fc < 8; ++fc){
      #pragma unroll
      for (int r = 0; r < 4; ++r){
        int row = lg*4 + r;                    // row>>2 == lg
        int cb = ((fc*16 + l15)*4) ^ ((lg & 1) << 6);
        *(float*)(slab + row*512 + cb) = acc[fr][fc][r];
      }
    }
    asm volatile("s_waitcnt lgkmcnt(0)" ::: "memory");
    __builtin_amdgcn_sched_barrier(0);
    #pragma unroll
    for (int i = 0; i < 4; ++i){
      const int it = fr*4 + i;
      ushort4& cp0 = (it & 1) ? pB0 : pA0;
      ushort4& cp1 = (it & 1) ? pB1 : pA1;
      ushort4& cq0 = (it & 1) ? qB0 : qA0;
      ushort4& cq1 = (it & 1) ? qB1 : qA1;
      int row = i*4 + lg;                      // row>>2 == i
      int grow = m0 + fr*16 + row;
      float4 v0 = *(const float4*)(slab + row*512 + ((l15*16) ^ ((i & 1) << 6)));
      float4 v1 = *(const float4*)(slab + row*512 + ((256 + l15*16) ^ ((i & 1) << 6)));
      ushort4 h0, h1;
      h0.x = f2bf(mishf(v0.x + bf2f(cp0.x) + bf2f(cq0.x) + b1v0.x));
      h0.y = f2bf(mishf(v0.y + bf2f(cp0.y) + bf2f(cq0.y) + b1v0.y));
      h0.z = f2bf(mishf(v0.z + bf2f(cp0.z) + bf2f(cq0.z) + b1v0.z));
      h0.w = f2bf(mishf(v0.w + bf2f(cp0.w) + bf2f(cq0.w) + b1v0.w));
      h1.x = f2bf(mishf(v1.x + bf2f(cp1.x) + bf2f(cq1.x) + b1v1.x));
      h1.y = f2bf(mishf(v1.y + bf2f(cp1.y) + bf2f(cq1.y) + b1v1.y));
      h1.z = f2bf(mishf(v1.z + bf2f(cp1.z) + bf2f(cq1.z) + b1v1.z));
      h1.w = f2bf(mishf(v1.w + bf2f(cp1.w) + bf2f(cq1.w) + b1v1.w));
      size_t hrow = (size_t)(grow - crowOff) * HID + wv*128;
      *(ushort4*)(hb + hrow + l15*4) = h0;
      *(ushort4*)(hb + hrow + 64 + l15*4) = h1;
      if (it + 2 < 8)
        LDPQ(sA[it+2], dA[it+2], cp0, cp1, cq0, cq1);
    }
    asm volatile("s_waitcnt lgkmcnt(0)" ::: "memory");
    __builtin_amdgcn_sched_barrier(0);
  }
}

// ---- CSR gather-reduce with deferred bias+mish; final chunk also writes aggb ----
__global__ __launch_bounds__(128)
void gather_agg(const uint16_t* __restrict__ msg, const int* __restrict__ rp,
                const float* __restrict__ b2, float* __restrict__ agg,
                uint16_t* __restrict__ aggb, int e0, int e1, int fin){
  const int n = blockIdx.x;
  int lo = rp[n], hi = rp[n+1];
  if (lo < e0) lo = e0;
  if (hi > e1) hi = e1;
  if (!fin && lo >= hi) return;
  const int t = threadIdx.x;
  const float4 bv = ((const float4*)b2)[t];
  float4 a = {0.f, 0.f, 0.f, 0.f};
  for (int e = lo; e < hi; ++e){
    ushort4 m = ((const ushort4*)(msg + (size_t)(e - e0) * HID))[t];
    a.x += mishf(bf2f(m.x) + bv.x);
    a.y += mishf(bf2f(m.y) + bv.y);
    a.z += mishf(bf2f(m.z) + bv.z);
    a.w += mishf(bf2f(m.w) + bv.w);
  }
  float4* ap = ((float4*)(agg + (size_t)n * HID)) + t;
  float4 c = *ap;
  c.x += a.x; c.y += a.y; c.z += a.z; c.w += a.w;
  if (lo < hi) *ap = c;
  if (fin){
    ushort4 o;
    o.x = f2bf(c.x); o.y = f2bf(c.y); o.z = f2bf(c.z); o.w = f2bf(c.w);
    ((ushort4*)(aggb + (size_t)n * HID))[t] = o;
  }
}

// ---------------- residual + LayerNorm ----------------
__global__ __launch_bounds__(128)
void resid_ln(const float* __restrict__ x, const float* __restrict__ ob,
              const float* __restrict__ gamma, const float* __restrict__ beta,
              float* __restrict__ y){
  const int row = blockIdx.x;
  const int t = threadIdx.x;
  const float4 xv = ((const float4*)(x + (size_t)row * HID))[t];
  const float4 ov = ((const float4*)(ob + (size_t)row * HID))[t];
  float4 s4;
  s4.x = xv.x + ov.x; s4.y = xv.y + ov.y; s4.z = xv.z + ov.z; s4.w = xv.w + ov.w;
  float s = s4.x + s4.y + s4.z + s4.w;
  float q = s4.x*s4.x + s4.y*s4.y + s4.z*s4.z + s4.w*s4.w;
  #pragma unroll
  for (int o = 32; o; o >>= 1){
    s += __shfl_xor(s, o, 64);
    q += __shfl_xor(q, o, 64);
  }
  __shared__ float ss[2], qq[2];
  if ((t & 63) == 0){ ss[t >> 6] = s; qq[t >> 6] = q; }
  __syncthreads();
  const float S = ss[0] + ss[1], Q = qq[0] + qq[1];
  const float mu = S * (1.0f / HID);
  const float var = Q * (1.0f / HID) - mu * mu;
  const float inv = rsqrtf(var + 1e-5f);
  const float4 g = ((const float4*)gamma)[t];
  const float4 b = ((const float4*)beta)[t];
  float4 o;
  o.x = (s4.x - mu) * inv * g.x + b.x;
  o.y = (s4.y - mu) * inv * g.y + b.y;
  o.z = (s4.z - mu) * inv * g.z + b.z;
  o.w = (s4.w - mu) * inv * g.w + b.w;
  ((float4*)(y + (size_t)row * HID))[t] = o;
}

extern "C" void kernel_launch(void* const* d_in, const int* in_sizes, int n_in,
                              void* d_out, int out_size, void* d_ws, size_t ws_size,
                              hipStream_t stream)
{
  const float* x    = (const float*)d_in[0];
  const int*   ei   = (const int*)d_in[1];
  const float* ea   = (const float*)d_in[2];
  const float* W1   = (const float*)d_in[3];
  const float* b1   = (const float*)d_in[4];
  const float* W2   = (const float*)d_in[5];
  const float* b2   = (const float*)d_in[6];
  const float* W3   = (const float*)d_in[7];
  const float* b3   = (const float*)d_in[8];
  const float* W4   = (const float*)d_in[9];
  const float* b4   = (const float*)d_in[10];
  const float* gmm  = (const float*)d_in[11];
  const float* bet  = (const float*)d_in[12];
  float* out = (float*)d_out;

  uint8_t* w = (uint8_t*)d_ws;
  size_t off = 0;
  auto alloc = [&](size_t bytes) -> void* {
    void* p = w + off;
    off += (bytes + 255) & ~(size_t)255;
    return p;
  };
  uint16_t* xb   = (uint16_t*)alloc((size_t)NNODES*HID*2);
  uint16_t* w1t  = (uint16_t*)alloc((size_t)HID*KFEAT*2);
  uint16_t* w2t  = (uint16_t*)alloc((size_t)HID*HID*2);
  uint16_t* w3t  = (uint16_t*)alloc((size_t)HID*1024*2);
  uint16_t* w4t  = (uint16_t*)alloc((size_t)HID*HID*2);
  uint16_t* PQb  = (uint16_t*)alloc((size_t)NNODES*1024*2);   // [n][1024]: P|Q
  float*    agg  = (float*)alloc((size_t)NNODES*HID*4);
  float*    outf = (float*)alloc((size_t)NNODES*HID*4);
  int*      srcN = (int*)alloc((size_t)NEDGES*4);
  int*      dstN = (int*)alloc((size_t)NEDGES*4);
  int*      idxS = (int*)alloc((size_t)NEDGES*4*3);  // [srcS | dstS | eidx]
  int*      cnt  = (int*)alloc((size_t)NNODES*4);
  int*      rp   = (int*)alloc((size_t)(NNODES+1)*4);
  int*      cur  = (int*)alloc((size_t)NNODES*4);
  int*      bsum = (int*)alloc((size_t)SB*4);
  int*      boff = (int*)alloc((size_t)SB*4);
  int*      flag = (int*)alloc(256);
  int*      srcS = idxS;
  int*      dstS = idxS + NEDGES;
  int*      eidx = idxS + 2*NEDGES;

  // Aliases (lifetime-checked):
  // eab (41 MB)   aliases outf  — eab dead before GEMM4 writes outf.
  // aggb (20.5MB) aliases PQb[0:half]  — PQb dead after last eh_k; aggb written after.
  // ub   (20.5MB) aliases PQb[half:]   — written by GEMM3 after aggb exists; disjoint.
  uint16_t* eab  = (uint16_t*)outf;
  uint16_t* aggb = PQb;
  uint16_t* ub   = PQb + (size_t)NNODES*HID;

  size_t remain = (ws_size > off) ? ws_size - off : 0;
  size_t maxChunk = remain / ((size_t)HID*2*2);    // hb + msgb
  long long chunkE = (long long)(maxChunk & ~(size_t)1023);
  if (chunkE > 107520) chunkE = 107520;            // exactly 3 chunks: amortize the
                                                   // per-chunk P-gather refetch (r14)
  if (chunkE < 1024) chunkE = 1024;
  uint16_t* hb   = (uint16_t*)alloc((size_t)chunkE*HID*2);
  uint16_t* msgb = (uint16_t*)alloc((size_t)chunkE*HID*2);

  hipMemsetAsync(agg, 0, (size_t)NNODES*HID*4, stream);
  hipMemsetAsync(cnt, 0, (size_t)NNODES*4, stream);
  hipMemsetAsync(flag, 0, 4, stream);

  detect_idx<<<64, 256, 0, stream>>>(ei, flag);
  norm_idx<<<(NEDGES+255)/256, 256, 0, stream>>>(ei, flag, srcN, dstN);
  hist_k<<<(NEDGES+255)/256, 256, 0, stream>>>(dstN, cnt);
  scan1<<<SB, 256, 0, stream>>>(cnt, rp, bsum);
  scan2<<<1, 64, 0, stream>>>(bsum, boff, rp + NNODES);
  scan3<<<SB, 256, 0, stream>>>(rp, boff, cur);
  permute_k<<<(NEDGES+255)/256, 256, 0, stream>>>(srcN, dstN, cur, srcS, eidx);
  fill_dstS<<<NNODES, 64, 0, stream>>>(rp, dstS);

  cast_bf16_vec<<<(NNODES*HID/4+255)/256, 256, 0, stream>>>((const float4*)x, (ushort4*)xb, NNODES*HID/4);
  cast_bf16_vec<<<(NEDGES*EDIM/4+255)/256, 256, 0, stream>>>((const float4*)ea, (ushort4*)eab, NEDGES*EDIM/4);

  transpose_cast<<<dim3((KFEAT+63)/64, (HID+63)/64), 256, 0, stream>>>(W1, w1t, KFEAT, HID);
  transpose_cast<<<dim3((HID+63)/64,  (HID+63)/64), 256, 0, stream>>>(W2, w2t, HID, HID);
  transpose_cast<<<dim3((1024+63)/64, (HID+63)/64), 256, 0, stream>>>(W3, w3t, 1024, HID);
  transpose_cast<<<dim3((HID+63)/64,  (HID+63)/64), 256, 0, stream>>>(W4, w4t, HID, HID);

  // Fused P|Q = x @ [W1a | W1b]  (N=1024, bf16 output, no bias/act)
  // nty=160 (%8==0 -> XCD grouping; padded tiles clamp rows, write-guarded)
  dim3 gpq(1024/128, 160);
  gemm_k<AM_DIR, EP_BF16L, HID, 1><<<gpq, 256, 0, stream>>>(
      xb, nullptr, w1t, b1, PQb, nullptr, KFEAT, 1024, 0, NNODES, 0);

  for (long long e0 = 0; e0 < NEDGES; e0 += chunkE){
    int ce = (int)((NEDGES - e0 < chunkE) ? (NEDGES - e0) : chunkE);
    int fin = (e0 + chunkE >= NEDGES) ? 1 : 0;
    // EH: h = mish(ea@W1c + P[src] + Q[dst] + b1) -> hb (chunk-local)
    eh_k<<<(ce+31)/32, 256, 0, stream>>>(eab, PQb, idxS, w1t, b1, hb, (int)e0, (int)e0);
    // GEMM2: hb @ W2 -> raw bf16 msgb (bias+mish deferred to gather)
    dim3 g2(HID/128, (ce+127)/128);
    gemm_k<AM_DIR, EP_RAW, HID, 0><<<g2, 256, 0, stream>>>(
        hb, nullptr, w2t, b2, msgb, nullptr, HID, HID, 0, ce, 0);
    // CSR gather-reduce: agg[n] += mish(msg + b2); final chunk also emits aggb
    gather_agg<<<NNODES, 128, 0, stream>>>(msgb, rp, b2, agg, aggb,
                                           (int)e0, (int)(e0+ce), fin);
  }

  dim3 g3(HID/128, 160);
  gemm_k<AM_NODE, EP_BF16, 1024, 0><<<g3, 256, 0, stream>>>(
      xb, aggb, w3t, b3, ub, nullptr, 1024, HID, 0, NNODES, 0);
  gemm_k<AM_DIR, EP_F32, HID, 0><<<g3, 256, 0, stream>>>(
      ub, nullptr, w4t, b4, nullptr, outf, HID, HID, 0, NNODES, 0);

  resid_ln<<<NNODES, 128, 0, stream>>>(x, outf, gmm, bet, out);
}

// Round 16
// 883.706 us; speedup vs baseline: 1.0355x; 1.0138x over previous
//
#include <hip/hip_runtime.h>
#include <cstdint>
#include <cstddef>

#define NNODES 20000
#define NEDGES 320000
#define HID 512
#define EDIM 64
#define KFEAT (2*HID + EDIM)   // 1088
#define SB 80
#define SSEG 250               // SB*SSEG == NNODES

typedef __bf16 bf16x8 __attribute__((ext_vector_type(8)));
typedef short short8 __attribute__((ext_vector_type(8)));
typedef float f32x4 __attribute__((ext_vector_type(4)));

#define AM_NODE 1
#define AM_DIR  2
#define EP_BF16    0   // +bias, mish, bf16 store
#define EP_F32     2   // +bias, raw f32 store
#define EP_BF16L   3   // no bias, no mish, bf16 store
#define EP_RAW     5   // raw f2bf(acc) store (bias+mish deferred to consumer)

__device__ __forceinline__ uint16_t f2bf(float f){
  uint32_t u = __float_as_uint(f);
  u += 0x7FFFu + ((u >> 16) & 1u);
  return (uint16_t)(u >> 16);
}
__device__ __forceinline__ float bf2f(uint16_t h){
  return __uint_as_float((uint32_t)h << 16);
}
// mish(x) = x * tanh(softplus(x)) = x * (e^2+2e)/(e^2+2e+2), e = exp(x)
__device__ __forceinline__ float mishf(float v){
  float e = __expf(fminf(v, 18.f));
  float n = e * (e + 2.f);
  return v * __fdividef(n, n + 2.f);
}
__device__ __forceinline__ void gl_lds16(const void* g, void* l){
  __builtin_amdgcn_global_load_lds(
      (const __attribute__((address_space(1))) uint32_t*)g,
      (__attribute__((address_space(3))) uint32_t*)l, 16, 0, 0);
}

// ---------------- index dtype detect / normalize ----------------
__global__ void detect_idx(const int* __restrict__ e, int* __restrict__ flag){
  int i = blockIdx.x * 256 + threadIdx.x;   // probe first 16384 pairs
  if (e[2*i + 1] != 0) atomicOr(flag, 1);   // flag=1 -> int32 layout
}
__global__ void norm_idx(const int* __restrict__ e, const int* __restrict__ flag,
                         int* __restrict__ s, int* __restrict__ d){
  int i = blockIdx.x * 256 + threadIdx.x;
  if (i >= NEDGES) return;
  int sv, dv;
  if (*flag){ sv = e[i];     dv = e[NEDGES + i]; }
  else      { sv = e[2*i];   dv = e[2*NEDGES + 2*i]; }   // int64 lo words
  sv = sv < 0 ? 0 : (sv > NNODES-1 ? NNODES-1 : sv);
  dv = dv < 0 ? 0 : (dv > NNODES-1 ? NNODES-1 : dv);
  s[i] = sv; d[i] = dv;
}

// ---------------- counting sort by dst (single permutation) ----------------
__global__ void hist_k(const int* __restrict__ d, int* __restrict__ cnt){
  int i = blockIdx.x * 256 + threadIdx.x;
  if (i < NEDGES) atomicAdd(&cnt[d[i]], 1);
}
// Multi-block exclusive scan over cnt[NNODES]: scan1 (per-block) -> scan2 (block
// offsets, serial over 80) -> scan3 (apply offsets, emit rp & cur).
__global__ __launch_bounds__(256)
void scan1(const int* __restrict__ cnt, int* __restrict__ rp, int* __restrict__ bsum){
  __shared__ int sh[256];
  const int b = blockIdx.x, t = threadIdx.x;
  int v = (t < SSEG) ? cnt[b*SSEG + t] : 0;
  sh[t] = v; __syncthreads();
  for (int o = 1; o < 256; o <<= 1){
    int u = (t >= o) ? sh[t-o] : 0;
    __syncthreads();
    sh[t] += u;
    __syncthreads();
  }
  if (t < SSEG) rp[b*SSEG + t] = sh[t] - v;   // exclusive local prefix
  if (t == 255) bsum[b] = sh[255];
}
__global__ void scan2(const int* __restrict__ bsum, int* __restrict__ boff,
                      int* __restrict__ rpN){
  if (threadIdx.x == 0){
    int acc = 0;
    for (int i = 0; i < SB; ++i){ boff[i] = acc; acc += bsum[i]; }
    *rpN = acc;
  }
}
__global__ __launch_bounds__(256)
void scan3(int* __restrict__ rp, const int* __restrict__ boff, int* __restrict__ cur){
  const int b = blockIdx.x, t = threadIdx.x;
  if (t < SSEG){
    int i = b*SSEG + t;
    int v = rp[i] + boff[b];
    rp[i] = v; cur[i] = v;
  }
}
// ONE permutation: sorted position p gets src id AND original edge id.
__global__ void permute_k(const int* __restrict__ srcN, const int* __restrict__ dstN,
                          int* __restrict__ cur, int* __restrict__ srcS,
                          int* __restrict__ eidx){
  int i = blockIdx.x * 256 + threadIdx.x;
  if (i < NEDGES){
    int d = dstN[i];
    int p = atomicAdd(&cur[d], 1);
    srcS[p] = srcN[i];
    eidx[p] = i;
  }
}
__global__ void fill_dstS(const int* __restrict__ rp, int* __restrict__ dstS){
  int n = blockIdx.x;
  int lo = rp[n], hi = rp[n+1];
  for (int e = lo + threadIdx.x; e < hi; e += 64) dstS[e] = n;
}

// ---------------- casts ----------------
__global__ void cast_bf16_vec(const float4* __restrict__ in, ushort4* __restrict__ out, int n4){
  int i = blockIdx.x * 256 + threadIdx.x;
  if (i < n4){
    float4 v = in[i];
    ushort4 o; o.x = f2bf(v.x); o.y = f2bf(v.y); o.z = f2bf(v.z); o.w = f2bf(v.w);
    out[i] = o;
  }
}
// Tiled transpose+cast: WT[n*K+k] = bf16(W[k*N+n]); coalesced on both sides.
__global__ __launch_bounds__(256)
void transpose_cast(const float* __restrict__ W, uint16_t* __restrict__ WT, int K, int N){
  __shared__ uint16_t tile[64][65];
  const int k0 = blockIdx.x * 64;
  const int n0 = blockIdx.y * 64;
  const int c = threadIdx.x & 63;
  const int r0 = threadIdx.x >> 6;    // 0..3
  #pragma unroll
  for (int rr = 0; rr < 64; rr += 4){
    int k = k0 + rr + r0, n = n0 + c;
    if (k < K && n < N) tile[rr + r0][c] = f2bf(W[(size_t)k*N + n]);
  }
  __syncthreads();
  #pragma unroll
  for (int rr = 0; rr < 64; rr += 4){
    int n = n0 + rr + r0, k = k0 + c;
    if (n < N && k < K) WT[(size_t)n*K + k] = tile[c][rr + r0];
  }
}

// ---------------- fused MFMA GEMM (128x128 tile, BK=64, 4 waves) ----------------
// Block remap: when nty%8==0, group row panels per XCD (flat%8 == XCD round-robin):
//   xcd = flat&7, i = flat>>3, by = xcd*(nty/8) + i/ntx, bx = i%ntx
// AM_NODE: row gm = [xb[gm] | aggb[gm]]  (K = 1024)
// AM_DIR : row-major A0, stride KTOT
// BPQ=1  : B^T row n -> w1t + (n&511)*bstr + (n>>9)*512  (fused P|Q, N=1024)
template<int AMODE, int EPI, int KTOT, int BPQ>
__global__ __launch_bounds__(256, 2)
void gemm_k(const uint16_t* __restrict__ A0, const uint16_t* __restrict__ A1,
            const uint16_t* __restrict__ BT, const float* __restrict__ bias,
            uint16_t* __restrict__ Cb, float* __restrict__ Cf,
            int bstr, int cstr, int m0base, int M, int crowOff)
{
  __shared__ __align__(16) char smem[32768];
  char* As = smem;
  char* Bs = smem + 16384;
  const int t = threadIdx.x;
  const int ntx = gridDim.x, nty = gridDim.y;
  int bx = blockIdx.x, by = blockIdx.y;
  if ((nty & 7) == 0){
    int flat = by * ntx + bx;
    int xcd = flat & 7;
    int i = flat >> 3;
    by = xcd * (nty >> 3) + i / ntx;
    bx = i % ntx;
  }
  const int m0 = m0base + by * 128;
  const int n0 = bx * 128;
  const int srow = t >> 3;
  const int c8   = t & 7;
  const int scol = ((c8 ^ (srow & 7)) << 3);
  const int ldst = srow * 128 + c8 * 16;

  const uint16_t* as0[4]; const uint16_t* as1[4];
  #pragma unroll
  for (int i = 0; i < 4; ++i){
    int gm = m0 + srow + 32*i;
    if (gm > M - 1) gm = M - 1;
    if (AMODE == AM_NODE){
      as0[i] = A0 + (size_t)gm * HID;
      as1[i] = A1 + (size_t)gm * HID;
    } else {
      as0[i] = A0 + (size_t)gm * KTOT;
      as1[i] = A0;
    }
  }
  const uint16_t* brow[4];
  #pragma unroll
  for (int i = 0; i < 4; ++i){
    int nr = n0 + srow + 32*i;
    if (BPQ) brow[i] = BT + (size_t)(nr & (HID-1))*bstr + (nr >> 9)*HID;
    else     brow[i] = BT + (size_t)nr*bstr;
  }

  const int lane = t & 63;
  const int wv = t >> 6;
  const int wm = (wv >> 1) * 64;
  const int wn = (wv & 1) * 64;
  const int l15 = lane & 15;
  const int lk16 = (lane >> 4) << 4;
  const int swz = (l15 & 7) << 4;

  f32x4 acc[4][4] = {};

  const int NK = KTOT / 64;
  for (int kk = 0; kk < NK; ++kk){
    const int k0 = kk * 64;
    #pragma unroll
    for (int i = 0; i < 4; ++i){
      const uint16_t* g;
      if (AMODE == AM_NODE){
        g = (k0 < HID) ? as0[i] + (k0 + scol) : as1[i] + (k0 - HID + scol);
      } else {
        g = as0[i] + (k0 + scol);
      }
      gl_lds16(g, As + i*4096 + ldst);
    }
    #pragma unroll
    for (int i = 0; i < 4; ++i)
      gl_lds16(brow[i] + (k0 + scol), Bs + i*4096 + ldst);
    __syncthreads();
    #pragma unroll
    for (int ks = 0; ks < 2; ++ks){
      bf16x8 af[4], bfr[4];
      #pragma unroll
      for (int i = 0; i < 4; ++i){
        const int ar = wm + i*16 + l15;
        af[i] = *(const bf16x8*)(As + ar*128 + ((ks*64 + lk16) ^ swz));
      }
      #pragma unroll
      for (int j = 0; j < 4; ++j){
        const int br = wn + j*16 + l15;
        bfr[j] = *(const bf16x8*)(Bs + br*128 + ((ks*64 + lk16) ^ swz));
      }
      #pragma unroll
      for (int i = 0; i < 4; ++i)
        #pragma unroll
        for (int j = 0; j < 4; ++j)
          acc[i][j] = __builtin_amdgcn_mfma_f32_16x16x32_bf16(af[i], bfr[j], acc[i][j], 0, 0, 0);
    }
    __syncthreads();
  }

  #pragma unroll
  for (int i = 0; i < 4; ++i){
    const int rb = wm + i*16 + ((lane >> 4) << 2);
    #pragma unroll
    for (int j = 0; j < 4; ++j){
      const int gcol = n0 + wn + j*16 + l15;
      const float bv = (EPI == EP_BF16L || EPI == EP_RAW) ? 0.f : bias[gcol];
      #pragma unroll
      for (int r = 0; r < 4; ++r){
        const int grow = m0 + rb + r;
        if (grow < M){
          float v = acc[i][j][r] + bv;
          if (EPI == EP_BF16){
            Cb[(size_t)(grow - crowOff) * cstr + gcol] = f2bf(mishf(v));
          } else if (EPI == EP_BF16L || EPI == EP_RAW){
            Cb[(size_t)(grow - crowOff) * cstr + gcol] = f2bf(v);
          } else {
            Cf[(size_t)grow * cstr + gcol] = v;
          }
        }
      }
    }
  }
}

// ---------------- EH: h = mish(ea@W1c + P[src] + Q[dst] + b1) ----------------
// 256 threads = 4 waves; block = 32 edges x 512 cols; wave wv owns cols [wv*128, +128).
// Indices preloaded; P/Q double-buffered depth 2 (it=0,1 issued before MFMA phase).
__global__ __launch_bounds__(256, 4)
void eh_k(const uint16_t* __restrict__ eab, const uint16_t* __restrict__ PQb,
          const int* __restrict__ idx,
          const uint16_t* __restrict__ w1t, const float* __restrict__ b1,
          uint16_t* __restrict__ hb, int m0base, int crowOff)
{
  __shared__ __align__(16) char smem[32768];   // 4 waves x 8KB (16 rows x 512B)
  const int t = threadIdx.x;
  const int m0 = m0base + blockIdx.x * 32;
  const int lane = t & 63;
  const int wv = t >> 6;
  const int l15 = lane & 15;
  const int lg = lane >> 4;                    // 0..3
  const int* srcS = idx;
  const int* dstS = idx + NEDGES;
  const int* eidx = idx + 2*NEDGES;

  int eidxr[2];
  #pragma unroll
  for (int fr = 0; fr < 2; ++fr) eidxr[fr] = eidx[m0 + fr*16 + l15];

  int sA[8], dA[8];
  #pragma unroll
  for (int it = 0; it < 8; ++it){
    int row2 = (it & 3)*4 + lg;
    int g = m0 + (it >> 2)*16 + row2;
    sA[it] = srcS[g];
    dA[it] = dstS[g];
  }

  const int pqoff = wv*128 + l15*4;
  ushort4 pA0, pA1, qA0, qA1;    // even iterations
  ushort4 pB0, pB1, qB0, qB1;    // odd iterations
  auto LDPQ = [&](int s, int d, ushort4& p0, ushort4& p1, ushort4& q0, ushort4& q1){
    const uint16_t* pb = PQb + (size_t)s*1024 + pqoff;
    const uint16_t* qb = PQb + (size_t)d*1024 + 512 + pqoff;
    p0 = *(const ushort4*)pb;  p1 = *(const ushort4*)(pb + 64);
    q0 = *(const ushort4*)qb;  q1 = *(const ushort4*)(qb + 64);
  };
  LDPQ(sA[0], dA[0], pA0, pA1, qA0, qA1);     // hides under MFMA phase
  LDPQ(sA[1], dA[1], pB0, pB1, qB0, qB1);

  f32x4 acc[2][8] = {};
  #pragma unroll
  for (int ks = 0; ks < 2; ++ks){
    bf16x8 bF[8];
    #pragma unroll
    for (int fc = 0; fc < 8; ++fc){
      int n = wv*128 + fc*16 + l15;
      bF[fc] = *(const bf16x8*)(w1t + (size_t)n*KFEAT + 2*HID + ks*32 + lg*8);
    }
    #pragma unroll
    for (int fr = 0; fr < 2; ++fr){
      bf16x8 av = *(const bf16x8*)(eab + (size_t)eidxr[fr]*EDIM + ks*32 + lg*8);
      #pragma unroll
      for (int fc = 0; fc < 8; ++fc)
        acc[fr][fc] = __builtin_amdgcn_mfma_f32_16x16x32_bf16(av, bF[fc], acc[fr][fc], 0, 0, 0);
    }
  }

  // ---- epilogue: slab transpose + depth-2 pipelined P/Q + mish + store
  char* slab = smem + wv*8192;
  const float4 b1v0 = *(const float4*)(b1 + wv*128 + l15*4);
  const float4 b1v1 = *(const float4*)(b1 + wv*128 + 64 + l15*4);
  #pragma unroll
  for (int fr = 0; fr < 2; ++fr){
    #pragma unroll
    for (int fc = 0; fc < 8; ++fc){
      #pragma unroll
      for (int r = 0; r < 4; ++r){
        int row = lg*4 + r;                    // row>>2 == lg
        int cb = ((fc*16 + l15)*4) ^ ((lg & 1) << 6);
        *(float*)(slab + row*512 + cb) = acc[fr][fc][r];
      }
    }
    asm volatile("s_waitcnt lgkmcnt(0)" ::: "memory");
    __builtin_amdgcn_sched_barrier(0);
    #pragma unroll
    for (int i = 0; i < 4; ++i){
      const int it = fr*4 + i;
      ushort4& cp0 = (it & 1) ? pB0 : pA0;
      ushort4& cp1 = (it & 1) ? pB1 : pA1;
      ushort4& cq0 = (it & 1) ? qB0 : qA0;
      ushort4& cq1 = (it & 1) ? qB1 : qA1;
      int row = i*4 + lg;                      // row>>2 == i
      int grow = m0 + fr*16 + row;
      float4 v0 = *(const float4*)(slab + row*512 + ((l15*16) ^ ((i & 1) << 6)));
      float4 v1 = *(const float4*)(slab + row*512 + ((256 + l15*16) ^ ((i & 1) << 6)));
      ushort4 h0, h1;
      h0.x = f2bf(mishf(v0.x + bf2f(cp0.x) + bf2f(cq0.x) + b1v0.x));
      h0.y = f2bf(mishf(v0.y + bf2f(cp0.y) + bf2f(cq0.y) + b1v0.y));
      h0.z = f2bf(mishf(v0.z + bf2f(cp0.z) + bf2f(cq0.z) + b1v0.z));
      h0.w = f2bf(mishf(v0.w + bf2f(cp0.w) + bf2f(cq0.w) + b1v0.w));
      h1.x = f2bf(mishf(v1.x + bf2f(cp1.x) + bf2f(cq1.x) + b1v1.x));
      h1.y = f2bf(mishf(v1.y + bf2f(cp1.y) + bf2f(cq1.y) + b1v1.y));
      h1.z = f2bf(mishf(v1.z + bf2f(cp1.z) + bf2f(cq1.z) + b1v1.z));
      h1.w = f2bf(mishf(v1.w + bf2f(cp1.w) + bf2f(cq1.w) + b1v1.w));
      size_t hrow = (size_t)(grow - crowOff) * HID + wv*128;
      *(ushort4*)(hb + hrow + l15*4) = h0;
      *(ushort4*)(hb + hrow + 64 + l15*4) = h1;
      if (it + 2 < 8)
        LDPQ(sA[it+2], dA[it+2], cp0, cp1, cq0, cq1);
    }
    asm volatile("s_waitcnt lgkmcnt(0)" ::: "memory");
    __builtin_amdgcn_sched_barrier(0);
  }
}

// ---- CSR gather-reduce, 256 threads/node: two row-parity halves accumulate ----
// stride-2 rows independently (serial chain halved), combine via LDS, write once.
__global__ __launch_bounds__(256)
void gather_agg(const uint16_t* __restrict__ msg, const int* __restrict__ rp,
                const float* __restrict__ b2, float* __restrict__ agg,
                uint16_t* __restrict__ aggb, int e0, int e1, int fin){
  const int n = blockIdx.x;
  int lo = rp[n], hi = rp[n+1];
  if (lo < e0) lo = e0;
  if (hi > e1) hi = e1;
  if (!fin && lo >= hi) return;
  const int t = threadIdx.x & 127;      // col group: 128 x float4 = 512 cols
  const int rh = threadIdx.x >> 7;      // row parity 0/1
  const float4 bv = ((const float4*)b2)[t];
  float4 a = {0.f, 0.f, 0.f, 0.f};
  for (int e = lo + rh; e < hi; e += 2){
    ushort4 m = ((const ushort4*)(msg + (size_t)(e - e0) * HID))[t];
    a.x += mishf(bf2f(m.x) + bv.x);
    a.y += mishf(bf2f(m.y) + bv.y);
    a.z += mishf(bf2f(m.z) + bv.z);
    a.w += mishf(bf2f(m.w) + bv.w);
  }
  __shared__ float4 red[128];
  if (rh == 1) red[t] = a;
  __syncthreads();
  if (rh == 0){
    float4 o = red[t];
    a.x += o.x; a.y += o.y; a.z += o.z; a.w += o.w;
    float4* ap = ((float4*)(agg + (size_t)n * HID)) + t;
    float4 c = *ap;
    c.x += a.x; c.y += a.y; c.z += a.z; c.w += a.w;
    if (lo < hi) *ap = c;
    if (fin){
      ushort4 ob;
      ob.x = f2bf(c.x); ob.y = f2bf(c.y); ob.z = f2bf(c.z); ob.w = f2bf(c.w);
      ((ushort4*)(aggb + (size_t)n * HID))[t] = ob;
    }
  }
}

// ---------------- residual + LayerNorm ----------------
__global__ __launch_bounds__(128)
void resid_ln(const float* __restrict__ x, const float* __restrict__ ob,
              const float* __restrict__ gamma, const float* __restrict__ beta,
              float* __restrict__ y){
  const int row = blockIdx.x;
  const int t = threadIdx.x;
  const float4 xv = ((const float4*)(x + (size_t)row * HID))[t];
  const float4 ov = ((const float4*)(ob + (size_t)row * HID))[t];
  float4 s4;
  s4.x = xv.x + ov.x; s4.y = xv.y + ov.y; s4.z = xv.z + ov.z; s4.w = xv.w + ov.w;
  float s = s4.x + s4.y + s4.z + s4.w;
  float q = s4.x*s4.x + s4.y*s4.y + s4.z*s4.z + s4.w*s4.w;
  #pragma unroll
  for (int o = 32; o; o >>= 1){
    s += __shfl_xor(s, o, 64);
    q += __shfl_xor(q, o, 64);
  }
  __shared__ float ss[2], qq[2];
  if ((t & 63) == 0){ ss[t >> 6] = s; qq[t >> 6] = q; }
  __syncthreads();
  const float S = ss[0] + ss[1], Q = qq[0] + qq[1];
  const float mu = S * (1.0f / HID);
  const float var = Q * (1.0f / HID) - mu * mu;
  const float inv = rsqrtf(var + 1e-5f);
  const float4 g = ((const float4*)gamma)[t];
  const float4 b = ((const float4*)beta)[t];
  float4 o;
  o.x = (s4.x - mu) * inv * g.x + b.x;
  o.y = (s4.y - mu) * inv * g.y + b.y;
  o.z = (s4.z - mu) * inv * g.z + b.z;
  o.w = (s4.w - mu) * inv * g.w + b.w;
  ((float4*)(y + (size_t)row * HID))[t] = o;
}

extern "C" void kernel_launch(void* const* d_in, const int* in_sizes, int n_in,
                              void* d_out, int out_size, void* d_ws, size_t ws_size,
                              hipStream_t stream)
{
  const float* x    = (const float*)d_in[0];
  const int*   ei   = (const int*)d_in[1];
  const float* ea   = (const float*)d_in[2];
  const float* W1   = (const float*)d_in[3];
  const float* b1   = (const float*)d_in[4];
  const float* W2   = (const float*)d_in[5];
  const float* b2   = (const float*)d_in[6];
  const float* W3   = (const float*)d_in[7];
  const float* b3   = (const float*)d_in[8];
  const float* W4   = (const float*)d_in[9];
  const float* b4   = (const float*)d_in[10];
  const float* gmm  = (const float*)d_in[11];
  const float* bet  = (const float*)d_in[12];
  float* out = (float*)d_out;

  uint8_t* w = (uint8_t*)d_ws;
  size_t off = 0;
  auto alloc = [&](size_t bytes) -> void* {
    void* p = w + off;
    off += (bytes + 255) & ~(size_t)255;
    return p;
  };
  uint16_t* xb   = (uint16_t*)alloc((size_t)NNODES*HID*2);
  uint16_t* w1t  = (uint16_t*)alloc((size_t)HID*KFEAT*2);
  uint16_t* w2t  = (uint16_t*)alloc((size_t)HID*HID*2);
  uint16_t* w3t  = (uint16_t*)alloc((size_t)HID*1024*2);
  uint16_t* w4t  = (uint16_t*)alloc((size_t)HID*HID*2);
  uint16_t* PQb  = (uint16_t*)alloc((size_t)NNODES*1024*2);   // [n][1024]: P|Q
  float*    agg  = (float*)alloc((size_t)NNODES*HID*4);
  float*    outf = (float*)alloc((size_t)NNODES*HID*4);
  int*      srcN = (int*)alloc((size_t)NEDGES*4);
  int*      dstN = (int*)alloc((size_t)NEDGES*4);
  int*      idxS = (int*)alloc((size_t)NEDGES*4*3);  // [srcS | dstS | eidx]
  int*      cnt  = (int*)alloc((size_t)NNODES*4);
  int*      rp   = (int*)alloc((size_t)(NNODES+1)*4);
  int*      cur  = (int*)alloc((size_t)NNODES*4);
  int*      bsum = (int*)alloc((size_t)SB*4);
  int*      boff = (int*)alloc((size_t)SB*4);
  int*      flag = (int*)alloc(256);
  int*      srcS = idxS;
  int*      dstS = idxS + NEDGES;
  int*      eidx = idxS + 2*NEDGES;

  // Aliases (lifetime-checked):
  // eab (41 MB)   aliases outf  — eab dead before GEMM4 writes outf.
  // aggb (20.5MB) aliases PQb[0:half]  — PQb dead after last eh_k; aggb written after.
  // ub   (20.5MB) aliases PQb[half:]   — written by GEMM3 after aggb exists; disjoint.
  uint16_t* eab  = (uint16_t*)outf;
  uint16_t* aggb = PQb;
  uint16_t* ub   = PQb + (size_t)NNODES*HID;

  size_t remain = (ws_size > off) ? ws_size - off : 0;
  size_t maxChunk = remain / ((size_t)HID*2*2);    // hb + msgb
  long long chunkE = (long long)(maxChunk & ~(size_t)1023);
  if (chunkE > 107520) chunkE = 107520;            // exactly 3 chunks: amortize the
                                                   // per-chunk P-gather refetch (r14)
  if (chunkE < 1024) chunkE = 1024;
  uint16_t* hb   = (uint16_t*)alloc((size_t)chunkE*HID*2);
  uint16_t* msgb = (uint16_t*)alloc((size_t)chunkE*HID*2);

  hipMemsetAsync(agg, 0, (size_t)NNODES*HID*4, stream);
  hipMemsetAsync(cnt, 0, (size_t)NNODES*4, stream);
  hipMemsetAsync(flag, 0, 4, stream);

  detect_idx<<<64, 256, 0, stream>>>(ei, flag);
  norm_idx<<<(NEDGES+255)/256, 256, 0, stream>>>(ei, flag, srcN, dstN);
  hist_k<<<(NEDGES+255)/256, 256, 0, stream>>>(dstN, cnt);
  scan1<<<SB, 256, 0, stream>>>(cnt, rp, bsum);
  scan2<<<1, 64, 0, stream>>>(bsum, boff, rp + NNODES);
  scan3<<<SB, 256, 0, stream>>>(rp, boff, cur);
  permute_k<<<(NEDGES+255)/256, 256, 0, stream>>>(srcN, dstN, cur, srcS, eidx);
  fill_dstS<<<NNODES, 64, 0, stream>>>(rp, dstS);

  cast_bf16_vec<<<(NNODES*HID/4+255)/256, 256, 0, stream>>>((const float4*)x, (ushort4*)xb, NNODES*HID/4);
  cast_bf16_vec<<<(NEDGES*EDIM/4+255)/256, 256, 0, stream>>>((const float4*)ea, (ushort4*)eab, NEDGES*EDIM/4);

  transpose_cast<<<dim3((KFEAT+63)/64, (HID+63)/64), 256, 0, stream>>>(W1, w1t, KFEAT, HID);
  transpose_cast<<<dim3((HID+63)/64,  (HID+63)/64), 256, 0, stream>>>(W2, w2t, HID, HID);
  transpose_cast<<<dim3((1024+63)/64, (HID+63)/64), 256, 0, stream>>>(W3, w3t, 1024, HID);
  transpose_cast<<<dim3((HID+63)/64,  (HID+63)/64), 256, 0, stream>>>(W4, w4t, HID, HID);

  // Fused P|Q = x @ [W1a | W1b]  (N=1024, bf16 output, no bias/act)
  // nty=160 (%8==0 -> XCD grouping; padded tiles clamp rows, write-guarded)
  dim3 gpq(1024/128, 160);
  gemm_k<AM_DIR, EP_BF16L, HID, 1><<<gpq, 256, 0, stream>>>(
      xb, nullptr, w1t, b1, PQb, nullptr, KFEAT, 1024, 0, NNODES, 0);

  for (long long e0 = 0; e0 < NEDGES; e0 += chunkE){
    int ce = (int)((NEDGES - e0 < chunkE) ? (NEDGES - e0) : chunkE);
    int fin = (e0 + chunkE >= NEDGES) ? 1 : 0;
    // EH: h = mish(ea@W1c + P[src] + Q[dst] + b1) -> hb (chunk-local)
    eh_k<<<(ce+31)/32, 256, 0, stream>>>(eab, PQb, idxS, w1t, b1, hb, (int)e0, (int)e0);
    // GEMM2: hb @ W2 -> raw bf16 msgb (bias+mish deferred to gather)
    dim3 g2(HID/128, (ce+127)/128);
    gemm_k<AM_DIR, EP_RAW, HID, 0><<<g2, 256, 0, stream>>>(
        hb, nullptr, w2t, b2, msgb, nullptr, HID, HID, 0, ce, 0);
    // CSR gather-reduce: agg[n] += mish(msg + b2); final chunk also emits aggb
    gather_agg<<<NNODES, 256, 0, stream>>>(msgb, rp, b2, agg, aggb,
                                           (int)e0, (int)(e0+ce), fin);
  }

  dim3 g3(HID/128, 160);
  gemm_k<AM_NODE, EP_BF16, 1024, 0><<<g3, 256, 0, stream>>>(
      xb, aggb, w3t, b3, ub, nullptr, 1024, HID, 0, NNODES, 0);
  gemm_k<AM_DIR, EP_F32, HID, 0><<<g3, 256, 0, stream>>>(
      ub, nullptr, w4t, b4, nullptr, outf, HID, HID, 0, NNODES, 0);

  resid_ln<<<NNODES, 128, 0, stream>>>(x, outf, gmm, bet, out);
}

// Round 17
// 875.052 us; speedup vs baseline: 1.0457x; 1.0099x over previous
//
#include <hip/hip_runtime.h>
#include <cstdint>
#include <cstddef>

#define NNODES 20000
#define NEDGES 320000
#define HID 512
#define EDIM 64
#define KFEAT (2*HID + EDIM)   // 1088
#define SB 80
#define SSEG 250               // SB*SSEG == NNODES

typedef __bf16 bf16x8 __attribute__((ext_vector_type(8)));
typedef short short8 __attribute__((ext_vector_type(8)));
typedef float f32x4 __attribute__((ext_vector_type(4)));

#define AM_NODE 1
#define AM_DIR  2
#define EP_BF16    0   // +bias, mish, bf16 store
#define EP_F32     2   // +bias, raw f32 store
#define EP_BF16L   3   // no bias, no mish, bf16 store
#define EP_RAW     5   // raw f2bf(acc) store (bias+mish deferred to consumer)

__device__ __forceinline__ uint16_t f2bf(float f){
  uint32_t u = __float_as_uint(f);
  u += 0x7FFFu + ((u >> 16) & 1u);
  return (uint16_t)(u >> 16);
}
__device__ __forceinline__ float bf2f(uint16_t h){
  return __uint_as_float((uint32_t)h << 16);
}
// mish(x) = x * tanh(softplus(x)) = x * (e^2+2e)/(e^2+2e+2), e = exp(x)
__device__ __forceinline__ float mishf(float v){
  float e = __expf(fminf(v, 18.f));
  float n = e * (e + 2.f);
  return v * __fdividef(n, n + 2.f);
}
__device__ __forceinline__ void gl_lds16(const void* g, void* l){
  __builtin_amdgcn_global_load_lds(
      (const __attribute__((address_space(1))) uint32_t*)g,
      (__attribute__((address_space(3))) uint32_t*)l, 16, 0, 0);
}

// ---------------- index dtype detect / normalize ----------------
__global__ void detect_idx(const int* __restrict__ e, int* __restrict__ flag){
  int i = blockIdx.x * 256 + threadIdx.x;   // probe first 16384 pairs
  if (e[2*i + 1] != 0) atomicOr(flag, 1);   // flag=1 -> int32 layout
}
__global__ void norm_idx(const int* __restrict__ e, const int* __restrict__ flag,
                         int* __restrict__ s, int* __restrict__ d){
  int i = blockIdx.x * 256 + threadIdx.x;
  if (i >= NEDGES) return;
  int sv, dv;
  if (*flag){ sv = e[i];     dv = e[NEDGES + i]; }
  else      { sv = e[2*i];   dv = e[2*NEDGES + 2*i]; }   // int64 lo words
  sv = sv < 0 ? 0 : (sv > NNODES-1 ? NNODES-1 : sv);
  dv = dv < 0 ? 0 : (dv > NNODES-1 ? NNODES-1 : dv);
  s[i] = sv; d[i] = dv;
}

// ---------------- counting sort by dst (single permutation) ----------------
__global__ void hist_k(const int* __restrict__ d, int* __restrict__ cnt){
  int i = blockIdx.x * 256 + threadIdx.x;
  if (i < NEDGES) atomicAdd(&cnt[d[i]], 1);
}
// Multi-block exclusive scan over cnt[NNODES]: scan1 (per-block) -> scan2 (block
// offsets, serial over 80) -> scan3 (apply offsets, emit rp & cur).
__global__ __launch_bounds__(256)
void scan1(const int* __restrict__ cnt, int* __restrict__ rp, int* __restrict__ bsum){
  __shared__ int sh[256];
  const int b = blockIdx.x, t = threadIdx.x;
  int v = (t < SSEG) ? cnt[b*SSEG + t] : 0;
  sh[t] = v; __syncthreads();
  for (int o = 1; o < 256; o <<= 1){
    int u = (t >= o) ? sh[t-o] : 0;
    __syncthreads();
    sh[t] += u;
    __syncthreads();
  }
  if (t < SSEG) rp[b*SSEG + t] = sh[t] - v;   // exclusive local prefix
  if (t == 255) bsum[b] = sh[255];
}
__global__ void scan2(const int* __restrict__ bsum, int* __restrict__ boff,
                      int* __restrict__ rpN){
  if (threadIdx.x == 0){
    int acc = 0;
    for (int i = 0; i < SB; ++i){ boff[i] = acc; acc += bsum[i]; }
    *rpN = acc;
  }
}
__global__ __launch_bounds__(256)
void scan3(int* __restrict__ rp, const int* __restrict__ boff, int* __restrict__ cur){
  const int b = blockIdx.x, t = threadIdx.x;
  if (t < SSEG){
    int i = b*SSEG + t;
    int v = rp[i] + boff[b];
    rp[i] = v; cur[i] = v;
  }
}
// ONE permutation: sorted position p gets src id, dst id, AND original edge id.
__global__ void permute_k(const int* __restrict__ srcN, const int* __restrict__ dstN,
                          int* __restrict__ cur, int* __restrict__ srcS,
                          int* __restrict__ dstS, int* __restrict__ eidx){
  int i = blockIdx.x * 256 + threadIdx.x;
  if (i < NEDGES){
    int d = dstN[i];
    int p = atomicAdd(&cur[d], 1);
    srcS[p] = srcN[i];
    dstS[p] = d;
    eidx[p] = i;
  }
}

// ---------------- casts ----------------
__global__ void cast_bf16_vec(const float4* __restrict__ in, ushort4* __restrict__ out, int n4){
  int i = blockIdx.x * 256 + threadIdx.x;
  if (i < n4){
    float4 v = in[i];
    ushort4 o; o.x = f2bf(v.x); o.y = f2bf(v.y); o.z = f2bf(v.z); o.w = f2bf(v.w);
    out[i] = o;
  }
}
// Tiled transpose+cast: WT[n*K+k] = bf16(W[k*N+n]); coalesced on both sides.
__global__ __launch_bounds__(256)
void transpose_cast(const float* __restrict__ W, uint16_t* __restrict__ WT, int K, int N){
  __shared__ uint16_t tile[64][65];
  const int k0 = blockIdx.x * 64;
  const int n0 = blockIdx.y * 64;
  const int c = threadIdx.x & 63;
  const int r0 = threadIdx.x >> 6;    // 0..3
  #pragma unroll
  for (int rr = 0; rr < 64; rr += 4){
    int k = k0 + rr + r0, n = n0 + c;
    if (k < K && n < N) tile[rr + r0][c] = f2bf(W[(size_t)k*N + n]);
  }
  __syncthreads();
  #pragma unroll
  for (int rr = 0; rr < 64; rr += 4){
    int n = n0 + rr + r0, k = k0 + c;
    if (n < N && k < K) WT[(size_t)n*K + k] = tile[c][rr + r0];
  }
}

// ---------------- fused MFMA GEMM (128x128 tile, BK=64, 4 waves) ----------------
// Block remap: when nty%8==0, group row panels per XCD (flat%8 == XCD round-robin):
//   xcd = flat&7, i = flat>>3, by = xcd*(nty/8) + i/ntx, bx = i%ntx
// AM_NODE: row gm = [xb[gm] | aggb[gm]]  (K = 1024)
// AM_DIR : row-major A0, stride KTOT
// BPQ=1  : B^T row n -> w1t + (n&511)*bstr + (n>>9)*512  (fused P|Q, N=1024)
template<int AMODE, int EPI, int KTOT, int BPQ>
__global__ __launch_bounds__(256, 2)
void gemm_k(const uint16_t* __restrict__ A0, const uint16_t* __restrict__ A1,
            const uint16_t* __restrict__ BT, const float* __restrict__ bias,
            uint16_t* __restrict__ Cb, float* __restrict__ Cf,
            int bstr, int cstr, int m0base, int M, int crowOff)
{
  __shared__ __align__(16) char smem[32768];
  char* As = smem;
  char* Bs = smem + 16384;
  const int t = threadIdx.x;
  const int ntx = gridDim.x, nty = gridDim.y;
  int bx = blockIdx.x, by = blockIdx.y;
  if ((nty & 7) == 0){
    int flat = by * ntx + bx;
    int xcd = flat & 7;
    int i = flat >> 3;
    by = xcd * (nty >> 3) + i / ntx;
    bx = i % ntx;
  }
  const int m0 = m0base + by * 128;
  const int n0 = bx * 128;
  const int srow = t >> 3;
  const int c8   = t & 7;
  const int scol = ((c8 ^ (srow & 7)) << 3);
  const int ldst = srow * 128 + c8 * 16;

  const uint16_t* as0[4]; const uint16_t* as1[4];
  #pragma unroll
  for (int i = 0; i < 4; ++i){
    int gm = m0 + srow + 32*i;
    if (gm > M - 1) gm = M - 1;
    if (AMODE == AM_NODE){
      as0[i] = A0 + (size_t)gm * HID;
      as1[i] = A1 + (size_t)gm * HID;
    } else {
      as0[i] = A0 + (size_t)gm * KTOT;
      as1[i] = A0;
    }
  }
  const uint16_t* brow[4];
  #pragma unroll
  for (int i = 0; i < 4; ++i){
    int nr = n0 + srow + 32*i;
    if (BPQ) brow[i] = BT + (size_t)(nr & (HID-1))*bstr + (nr >> 9)*HID;
    else     brow[i] = BT + (size_t)nr*bstr;
  }

  const int lane = t & 63;
  const int wv = t >> 6;
  const int wm = (wv >> 1) * 64;
  const int wn = (wv & 1) * 64;
  const int l15 = lane & 15;
  const int lk16 = (lane >> 4) << 4;
  const int swz = (l15 & 7) << 4;

  f32x4 acc[4][4] = {};

  const int NK = KTOT / 64;
  for (int kk = 0; kk < NK; ++kk){
    const int k0 = kk * 64;
    #pragma unroll
    for (int i = 0; i < 4; ++i){
      const uint16_t* g;
      if (AMODE == AM_NODE){
        g = (k0 < HID) ? as0[i] + (k0 + scol) : as1[i] + (k0 - HID + scol);
      } else {
        g = as0[i] + (k0 + scol);
      }
      gl_lds16(g, As + i*4096 + ldst);
    }
    #pragma unroll
    for (int i = 0; i < 4; ++i)
      gl_lds16(brow[i] + (k0 + scol), Bs + i*4096 + ldst);
    __syncthreads();
    #pragma unroll
    for (int ks = 0; ks < 2; ++ks){
      bf16x8 af[4], bfr[4];
      #pragma unroll
      for (int i = 0; i < 4; ++i){
        const int ar = wm + i*16 + l15;
        af[i] = *(const bf16x8*)(As + ar*128 + ((ks*64 + lk16) ^ swz));
      }
      #pragma unroll
      for (int j = 0; j < 4; ++j){
        const int br = wn + j*16 + l15;
        bfr[j] = *(const bf16x8*)(Bs + br*128 + ((ks*64 + lk16) ^ swz));
      }
      #pragma unroll
      for (int i = 0; i < 4; ++i)
        #pragma unroll
        for (int j = 0; j < 4; ++j)
          acc[i][j] = __builtin_amdgcn_mfma_f32_16x16x32_bf16(af[i], bfr[j], acc[i][j], 0, 0, 0);
    }
    __syncthreads();
  }

  #pragma unroll
  for (int i = 0; i < 4; ++i){
    const int rb = wm + i*16 + ((lane >> 4) << 2);
    #pragma unroll
    for (int j = 0; j < 4; ++j){
      const int gcol = n0 + wn + j*16 + l15;
      const float bv = (EPI == EP_BF16L || EPI == EP_RAW) ? 0.f : bias[gcol];
      #pragma unroll
      for (int r = 0; r < 4; ++r){
        const int grow = m0 + rb + r;
        if (grow < M){
          float v = acc[i][j][r] + bv;
          if (EPI == EP_BF16){
            Cb[(size_t)(grow - crowOff) * cstr + gcol] = f2bf(mishf(v));
          } else if (EPI == EP_BF16L || EPI == EP_RAW){
            Cb[(size_t)(grow - crowOff) * cstr + gcol] = f2bf(v);
          } else {
            Cf[(size_t)grow * cstr + gcol] = v;
          }
        }
      }
    }
  }
}

// ---------------- EH: h = mish(ea@W1c + P[src] + Q[dst] + b1) ----------------
// 256 threads = 4 waves; block = 32 edges x 512 cols; wave wv owns cols [wv*128, +128).
// Indices preloaded; P/Q double-buffered depth 2 (it=0,1 issued before MFMA phase).
__global__ __launch_bounds__(256, 4)
void eh_k(const uint16_t* __restrict__ eab, const uint16_t* __restrict__ PQb,
          const int* __restrict__ idx,
          const uint16_t* __restrict__ w1t, const float* __restrict__ b1,
          uint16_t* __restrict__ hb, int m0base, int crowOff)
{
  __shared__ __align__(16) char smem[32768];   // 4 waves x 8KB (16 rows x 512B)
  const int t = threadIdx.x;
  const int m0 = m0base + blockIdx.x * 32;
  const int lane = t & 63;
  const int wv = t >> 6;
  const int l15 = lane & 15;
  const int lg = lane >> 4;                    // 0..3
  const int* srcS = idx;
  const int* dstS = idx + NEDGES;
  const int* eidx = idx + 2*NEDGES;

  int eidxr[2];
  #pragma unroll
  for (int fr = 0; fr < 2; ++fr) eidxr[fr] = eidx[m0 + fr*16 + l15];

  int sA[8], dA[8];
  #pragma unroll
  for (int it = 0; it < 8; ++it){
    int row2 = (it & 3)*4 + lg;
    int g = m0 + (it >> 2)*16 + row2;
    sA[it] = srcS[g];
    dA[it] = dstS[g];
  }

  const int pqoff = wv*128 + l15*4;
  ushort4 pA0, pA1, qA0, qA1;    // even iterations
  ushort4 pB0, pB1, qB0, qB1;    // odd iterations
  auto LDPQ = [&](int s, int d, ushort4& p0, ushort4& p1, ushort4& q0, ushort4& q1){
    const uint16_t* pb = PQb + (size_t)s*1024 + pqoff;
    const uint16_t* qb = PQb + (size_t)d*1024 + 512 + pqoff;
    p0 = *(const ushort4*)pb;  p1 = *(const ushort4*)(pb + 64);
    q0 = *(const ushort4*)qb;  q1 = *(const ushort4*)(qb + 64);
  };
  LDPQ(sA[0], dA[0], pA0, pA1, qA0, qA1);     // hides under MFMA phase
  LDPQ(sA[1], dA[1], pB0, pB1, qB0, qB1);

  f32x4 acc[2][8] = {};
  #pragma unroll
  for (int ks = 0; ks < 2; ++ks){
    bf16x8 bF[8];
    #pragma unroll
    for (int fc = 0; fc < 8; ++fc){
      int n = wv*128 + fc*16 + l15;
      bF[fc] = *(const bf16x8*)(w1t + (size_t)n*KFEAT + 2*HID + ks*32 + lg*8);
    }
    #pragma unroll
    for (int fr = 0; fr < 2; ++fr){
      bf16x8 av = *(const bf16x8*)(eab + (size_t)eidxr[fr]*EDIM + ks*32 + lg*8);
      #pragma unroll
      for (int fc = 0; fc < 8; ++fc)
        acc[fr][fc] = __builtin_amdgcn_mfma_f32_16x16x32_bf16(av, bF[fc], acc[fr][fc], 0, 0, 0);
    }
  }

  // ---- epilogue: slab transpose + depth-2 pipelined P/Q + mish + store
  char* slab = smem + wv*8192;
  const float4 b1v0 = *(const float4*)(b1 + wv*128 + l15*4);
  const float4 b1v1 = *(const float4*)(b1 + wv*128 + 64 + l15*4);
  #pragma unroll
  for (int fr = 0; fr < 2; ++fr){
    #pragma unroll
    for (int fc = 0; fc < 8; ++fc){
      #pragma unroll
      for (int r = 0; r < 4; ++r){
        int row = lg*4 + r;                    // row>>2 == lg
        int cb = ((fc*16 + l15)*4) ^ ((lg & 1) << 6);
        *(float*)(slab + row*512 + cb) = acc[fr][fc][r];
      }
    }
    asm volatile("s_waitcnt lgkmcnt(0)" ::: "memory");
    __builtin_amdgcn_sched_barrier(0);
    #pragma unroll
    for (int i = 0; i < 4; ++i){
      const int it = fr*4 + i;
      ushort4& cp0 = (it & 1) ? pB0 : pA0;
      ushort4& cp1 = (it & 1) ? pB1 : pA1;
      ushort4& cq0 = (it & 1) ? qB0 : qA0;
      ushort4& cq1 = (it & 1) ? qB1 : qA1;
      int row = i*4 + lg;                      // row>>2 == i
      int grow = m0 + fr*16 + row;
      float4 v0 = *(const float4*)(slab + row*512 + ((l15*16) ^ ((i & 1) << 6)));
      float4 v1 = *(const float4*)(slab + row*512 + ((256 + l15*16) ^ ((i & 1) << 6)));
      ushort4 h0, h1;
      h0.x = f2bf(mishf(v0.x + bf2f(cp0.x) + bf2f(cq0.x) + b1v0.x));
      h0.y = f2bf(mishf(v0.y + bf2f(cp0.y) + bf2f(cq0.y) + b1v0.y));
      h0.z = f2bf(mishf(v0.z + bf2f(cp0.z) + bf2f(cq0.z) + b1v0.z));
      h0.w = f2bf(mishf(v0.w + bf2f(cp0.w) + bf2f(cq0.w) + b1v0.w));
      h1.x = f2bf(mishf(v1.x + bf2f(cp1.x) + bf2f(cq1.x) + b1v1.x));
      h1.y = f2bf(mishf(v1.y + bf2f(cp1.y) + bf2f(cq1.y) + b1v1.y));
      h1.z = f2bf(mishf(v1.z + bf2f(cp1.z) + bf2f(cq1.z) + b1v1.z));
      h1.w = f2bf(mishf(v1.w + bf2f(cp1.w) + bf2f(cq1.w) + b1v1.w));
      size_t hrow = (size_t)(grow - crowOff) * HID + wv*128;
      *(ushort4*)(hb + hrow + l15*4) = h0;
      *(ushort4*)(hb + hrow + 64 + l15*4) = h1;
      if (it + 2 < 8)
        LDPQ(sA[it+2], dA[it+2], cp0, cp1, cq0, cq1);
    }
    asm volatile("s_waitcnt lgkmcnt(0)" ::: "memory");
    __builtin_amdgcn_sched_barrier(0);
  }
}

// ---- CSR gather-reduce, 256 threads/node: two row-parity halves accumulate ----
// stride-2 rows independently, combine via LDS, write once.
// first=1: agg is assigned (not accumulated) and every node writes -> no memset.
__global__ __launch_bounds__(256)
void gather_agg(const uint16_t* __restrict__ msg, const int* __restrict__ rp,
                const float* __restrict__ b2, float* __restrict__ agg,
                uint16_t* __restrict__ aggb, int e0, int e1, int first, int fin){
  const int n = blockIdx.x;
  int lo = rp[n], hi = rp[n+1];
  if (lo < e0) lo = e0;
  if (hi > e1) hi = e1;
  if (!fin && !first && lo >= hi) return;
  const int t = threadIdx.x & 127;      // col group: 128 x float4 = 512 cols
  const int rh = threadIdx.x >> 7;      // row parity 0/1
  const float4 bv = ((const float4*)b2)[t];
  float4 a = {0.f, 0.f, 0.f, 0.f};
  for (int e = lo + rh; e < hi; e += 2){
    ushort4 m = ((const ushort4*)(msg + (size_t)(e - e0) * HID))[t];
    a.x += mishf(bf2f(m.x) + bv.x);
    a.y += mishf(bf2f(m.y) + bv.y);
    a.z += mishf(bf2f(m.z) + bv.z);
    a.w += mishf(bf2f(m.w) + bv.w);
  }
  __shared__ float4 red[128];
  if (rh == 1) red[t] = a;
  __syncthreads();
  if (rh == 0){
    float4 o = red[t];
    a.x += o.x; a.y += o.y; a.z += o.z; a.w += o.w;
    float4* ap = ((float4*)(agg + (size_t)n * HID)) + t;
    float4 c;
    if (first){
      c = a;
    } else {
      c = *ap;
      c.x += a.x; c.y += a.y; c.z += a.z; c.w += a.w;
    }
    if (first || lo < hi) *ap = c;
    if (fin){
      ushort4 ob;
      ob.x = f2bf(c.x); ob.y = f2bf(c.y); ob.z = f2bf(c.z); ob.w = f2bf(c.w);
      ((ushort4*)(aggb + (size_t)n * HID))[t] = ob;
    }
  }
}

// ---------------- residual + LayerNorm ----------------
__global__ __launch_bounds__(128)
void resid_ln(const float* __restrict__ x, const float* __restrict__ ob,
              const float* __restrict__ gamma, const float* __restrict__ beta,
              float* __restrict__ y){
  const int row = blockIdx.x;
  const int t = threadIdx.x;
  const float4 xv = ((const float4*)(x + (size_t)row * HID))[t];
  const float4 ov = ((const float4*)(ob + (size_t)row * HID))[t];
  float4 s4;
  s4.x = xv.x + ov.x; s4.y = xv.y + ov.y; s4.z = xv.z + ov.z; s4.w = xv.w + ov.w;
  float s = s4.x + s4.y + s4.z + s4.w;
  float q = s4.x*s4.x + s4.y*s4.y + s4.z*s4.z + s4.w*s4.w;
  #pragma unroll
  for (int o = 32; o; o >>= 1){
    s += __shfl_xor(s, o, 64);
    q += __shfl_xor(q, o, 64);
  }
  __shared__ float ss[2], qq[2];
  if ((t & 63) == 0){ ss[t >> 6] = s; qq[t >> 6] = q; }
  __syncthreads();
  const float S = ss[0] + ss[1], Q = qq[0] + qq[1];
  const float mu = S * (1.0f / HID);
  const float var = Q * (1.0f / HID) - mu * mu;
  const float inv = rsqrtf(var + 1e-5f);
  const float4 g = ((const float4*)gamma)[t];
  const float4 b = ((const float4*)beta)[t];
  float4 o;
  o.x = (s4.x - mu) * inv * g.x + b.x;
  o.y = (s4.y - mu) * inv * g.y + b.y;
  o.z = (s4.z - mu) * inv * g.z + b.z;
  o.w = (s4.w - mu) * inv * g.w + b.w;
  ((float4*)(y + (size_t)row * HID))[t] = o;
}

extern "C" void kernel_launch(void* const* d_in, const int* in_sizes, int n_in,
                              void* d_out, int out_size, void* d_ws, size_t ws_size,
                              hipStream_t stream)
{
  const float* x    = (const float*)d_in[0];
  const int*   ei   = (const int*)d_in[1];
  const float* ea   = (const float*)d_in[2];
  const float* W1   = (const float*)d_in[3];
  const float* b1   = (const float*)d_in[4];
  const float* W2   = (const float*)d_in[5];
  const float* b2   = (const float*)d_in[6];
  const float* W3   = (const float*)d_in[7];
  const float* b3   = (const float*)d_in[8];
  const float* W4   = (const float*)d_in[9];
  const float* b4   = (const float*)d_in[10];
  const float* gmm  = (const float*)d_in[11];
  const float* bet  = (const float*)d_in[12];
  float* out = (float*)d_out;

  uint8_t* w = (uint8_t*)d_ws;
  size_t off = 0;
  auto alloc = [&](size_t bytes) -> void* {
    void* p = w + off;
    off += (bytes + 255) & ~(size_t)255;
    return p;
  };
  uint16_t* xb   = (uint16_t*)alloc((size_t)NNODES*HID*2);
  uint16_t* w1t  = (uint16_t*)alloc((size_t)HID*KFEAT*2);
  uint16_t* w2t  = (uint16_t*)alloc((size_t)HID*HID*2);
  uint16_t* w3t  = (uint16_t*)alloc((size_t)HID*1024*2);
  uint16_t* w4t  = (uint16_t*)alloc((size_t)HID*HID*2);
  uint16_t* PQb  = (uint16_t*)alloc((size_t)NNODES*1024*2);   // [n][1024]: P|Q
  float*    agg  = (float*)alloc((size_t)NNODES*HID*4);
  float*    outf = (float*)alloc((size_t)NNODES*HID*4);
  int*      srcN = (int*)alloc((size_t)NEDGES*4);
  int*      dstN = (int*)alloc((size_t)NEDGES*4);
  int*      idxS = (int*)alloc((size_t)NEDGES*4*3);  // [srcS | dstS | eidx]
  int*      cnt  = (int*)alloc((size_t)NNODES*4);
  int*      rp   = (int*)alloc((size_t)(NNODES+1)*4);
  int*      cur  = (int*)alloc((size_t)NNODES*4);
  int*      bsum = (int*)alloc((size_t)SB*4);
  int*      boff = (int*)alloc((size_t)SB*4);
  int*      flag = (int*)alloc(256);
  int*      srcS = idxS;
  int*      dstS = idxS + NEDGES;
  int*      eidx = idxS + 2*NEDGES;

  // Aliases (lifetime-checked):
  // eab (41 MB)   aliases outf  — eab dead before GEMM4 writes outf.
  // aggb (20.5MB) aliases PQb[0:half]  — PQb dead after last eh_k; aggb written after.
  // ub   (20.5MB) aliases PQb[half:]   — written by GEMM3 after aggb exists; disjoint.
  uint16_t* eab  = (uint16_t*)outf;
  uint16_t* aggb = PQb;
  uint16_t* ub   = PQb + (size_t)NNODES*HID;

  size_t remain = (ws_size > off) ? ws_size - off : 0;
  size_t maxChunk = remain / ((size_t)HID*2*2);    // hb + msgb
  long long chunkE = (long long)(maxChunk & ~(size_t)1023);
  if (chunkE > 107520) chunkE = 107520;            // exactly 3 chunks: amortize the
                                                   // per-chunk P-gather refetch (r14)
  if (chunkE < 1024) chunkE = 1024;
  uint16_t* hb   = (uint16_t*)alloc((size_t)chunkE*HID*2);
  uint16_t* msgb = (uint16_t*)alloc((size_t)chunkE*HID*2);

  hipMemsetAsync(cnt, 0, (size_t)NNODES*4, stream);
  hipMemsetAsync(flag, 0, 4, stream);

  detect_idx<<<64, 256, 0, stream>>>(ei, flag);
  norm_idx<<<(NEDGES+255)/256, 256, 0, stream>>>(ei, flag, srcN, dstN);
  hist_k<<<(NEDGES+255)/256, 256, 0, stream>>>(dstN, cnt);
  scan1<<<SB, 256, 0, stream>>>(cnt, rp, bsum);
  scan2<<<1, 64, 0, stream>>>(bsum, boff, rp + NNODES);
  scan3<<<SB, 256, 0, stream>>>(rp, boff, cur);
  permute_k<<<(NEDGES+255)/256, 256, 0, stream>>>(srcN, dstN, cur, srcS, dstS, eidx);

  cast_bf16_vec<<<(NNODES*HID/4+255)/256, 256, 0, stream>>>((const float4*)x, (ushort4*)xb, NNODES*HID/4);
  cast_bf16_vec<<<(NEDGES*EDIM/4+255)/256, 256, 0, stream>>>((const float4*)ea, (ushort4*)eab, NEDGES*EDIM/4);

  transpose_cast<<<dim3((KFEAT+63)/64, (HID+63)/64), 256, 0, stream>>>(W1, w1t, KFEAT, HID);
  transpose_cast<<<dim3((HID+63)/64,  (HID+63)/64), 256, 0, stream>>>(W2, w2t, HID, HID);
  transpose_cast<<<dim3((1024+63)/64, (HID+63)/64), 256, 0, stream>>>(W3, w3t, 1024, HID);
  transpose_cast<<<dim3((HID+63)/64,  (HID+63)/64), 256, 0, stream>>>(W4, w4t, HID, HID);

  // Fused P|Q = x @ [W1a | W1b]  (N=1024, bf16 output, no bias/act)
  // nty=160 (%8==0 -> XCD grouping; padded tiles clamp rows, write-guarded)
  dim3 gpq(1024/128, 160);
  gemm_k<AM_DIR, EP_BF16L, HID, 1><<<gpq, 256, 0, stream>>>(
      xb, nullptr, w1t, b1, PQb, nullptr, KFEAT, 1024, 0, NNODES, 0);

  for (long long e0 = 0; e0 < NEDGES; e0 += chunkE){
    int ce = (int)((NEDGES - e0 < chunkE) ? (NEDGES - e0) : chunkE);
    int first = (e0 == 0) ? 1 : 0;
    int fin = (e0 + chunkE >= NEDGES) ? 1 : 0;
    // EH: h = mish(ea@W1c + P[src] + Q[dst] + b1) -> hb (chunk-local)
    eh_k<<<(ce+31)/32, 256, 0, stream>>>(eab, PQb, idxS, w1t, b1, hb, (int)e0, (int)e0);
    // GEMM2: hb @ W2 -> raw bf16 msgb (bias+mish deferred to gather)
    dim3 g2(HID/128, (ce+127)/128);
    gemm_k<AM_DIR, EP_RAW, HID, 0><<<g2, 256, 0, stream>>>(
        hb, nullptr, w2t, b2, msgb, nullptr, HID, HID, 0, ce, 0);
    // CSR gather-reduce: agg[n] (+)= mish(msg + b2); first chunk assigns (no memset),
    // final chunk also emits aggb
    gather_agg<<<NNODES, 256, 0, stream>>>(msgb, rp, b2, agg, aggb,
                                           (int)e0, (int)(e0+ce), first, fin);
  }

  dim3 g3(HID/128, 160);
  gemm_k<AM_NODE, EP_BF16, 1024, 0><<<g3, 256, 0, stream>>>(
      xb, aggb, w3t, b3, ub, nullptr, 1024, HID, 0, NNODES, 0);
  gemm_k<AM_DIR, EP_F32, HID, 0><<<g3, 256, 0, stream>>>(
      ub, nullptr, w4t, b4, nullptr, outf, HID, HID, 0, NNODES, 0);

  resid_ln<<<NNODES, 128, 0, stream>>>(x, outf, gmm, bet, out);
}